// Round 5
// baseline (378.599 us; speedup 1.0000x reference)
//
#include <hip/hip_runtime.h>

#pragma clang fp contract(off)

typedef unsigned long long u64;
typedef unsigned int u32;
typedef unsigned short u16;

#define BATCH 8
#define NA 131072
#define NSEL 6000
#define NT 24                 // 256-box tiles
#define TILE 256
#define NWORD (NT * 4)        // 96 64-bit words
#define NPAD (NT * TILE)      // 6144
#define CAND_CAP 8192
#define PROP 1000
#define SCAP 4096             // cross-tile entries cap per (batch, DEST tile)
#define LDSE 12288            // entries staged in LDS (u32 each)
#define CELLCAP 256           // boxes per 8x8 grid cell (mean ~94)
#define LARGECAP 1024         // "large" boxes per batch (dim > 1/8)
#define LTHR 0.125f
#define NBLK 512              // mega kernel grid; co-residency capacity >= 1024

// ---- workspace layout (bytes); [0, MEMSET_BYTES) zeroed every launch ----
#define OFF_HIST     0            // BATCH*257*4 = 8224
#define OFF_BFILL    8256         // 8224 -> 16480
#define OFF_SCNT     16512        // BATCH*NT*4 = 768 -> 17280
#define OFF_CELLCNT  17344        // 2080 -> 19424
#define OFF_BAR      19456        // 6 ints (3 x {cnt,flag}) -> 19480
#define MEMSET_BYTES 19520
#define OFF_TILET    19520        // BATCH*NT*256*4*8 = 1572864 -> 1592384
#define OFF_CAND     1592384      // BATCH*8192*8 = 524288 -> 2116672
#define OFF_BOXES    2116672      // BATCH*6144*16 = 786432 -> 2903104
#define OFF_CELLLIST 2903104      // 262144 -> 3165248
#define OFF_LARGE    3165248      // 16384 -> 3181632
#define OFF_SENT     3181632      // BATCH*NT*SCAP*4 = 3145728 -> 6327360

__device__ __forceinline__ int bucket_of(u32 bits) {
  u32 hi = bits >> 16;
  if (hi >= 0x3E80u && hi < 0x3F80u) return (int)(hi - 0x3E80u);
  if (hi >= 0x3F80u && hi < 0x8000u) return 255;
  return -1;
}

// "RN32(inter / max(uni,1e-12)) > 0.7f" without fp32 divide, bit-exact:
// M=0x1.666667p-1 is the 0.7f/nextafter midpoint; RN32(t)>0.7f <=> t>=M;
// a/b>=M <=> a>=M*b, exact in fp64 (25-bit x 24-bit product).
__device__ __forceinline__ bool iou_gt(float4 A, float4 B, float areaA, float areaB) {
  float iy = fminf(A.z, B.z) - fmaxf(A.x, B.x);
  float ix = fminf(A.w, B.w) - fmaxf(A.y, B.y);
  float inter = fmaxf(iy, 0.0f) * fmaxf(ix, 0.0f);
  float uni = (areaA + areaB) - inter;
  float uc = fmaxf(uni, 1e-12f);
  return (double)inter >= 0x1.666667p-1 * (double)uc;
}

// Within-tile pairs -> dense bit matrix tileT[b][t][dst&255][(src&255)>>6].
// Cross-tile pairs -> u32 entry (src<<8)|(dst&255) in segment (b, dst_tile).
__device__ __forceinline__ void emit_pair(int b, int ra, int rb, u64* tileT,
                                          u32* sent, int* scnt) {
  int src = min(ra, rb), dst = max(ra, rb);
  int tsrc = src >> 8, tdst = dst >> 8;
  if (tsrc == tdst) {
    atomicOr(&tileT[(((size_t)b * NT + tdst) * TILE + (dst & 255)) * 4 + ((src >> 6) & 3)],
             1ULL << (src & 63));
  } else {
    int e = atomicAdd(&scnt[b * NT + tdst], 1);
    if (e < SCAP)
      sent[(size_t)(b * NT + tdst) * SCAP + e] = ((u32)src << 8) | (u32)(dst & 255);
  }
}

__device__ __forceinline__ u64 shfl_xor_u64(u64 v, int lanemask) {
  u32 lo = (u32)v, hi = (u32)(v >> 32);
  lo = (u32)__shfl_xor((int)lo, lanemask);
  hi = (u32)__shfl_xor((int)hi, lanemask);
  return ((u64)hi << 32) | (u64)lo;
}

__device__ __forceinline__ u64 valid_mask(int g) {
  int lo = g * 64;
  if (lo + 64 <= NSEL) return ~0ULL;
  if (lo >= NSEL) return 0ULL;
  return (1ULL << (NSEL - lo)) - 1ULL;
}

// single-use device-scope grid barrier (counters zeroed by the launch memset).
// All NBLK blocks are co-resident by construction (LDS 25.6KB -> 6 blk/CU,
// launch_bounds(256,4) -> VGPR<=128 -> >=4 blk/CU; capacity >= 1024 >= NBLK).
__device__ __forceinline__ void grid_barrier(int* bar, int idx) {
  __syncthreads();
  if (threadIdx.x == 0) {
    __threadfence();
    int a = __hip_atomic_fetch_add(&bar[idx * 2], 1, __ATOMIC_ACQ_REL,
                                   __HIP_MEMORY_SCOPE_AGENT);
    if (a == NBLK - 1) {
      __hip_atomic_store(&bar[idx * 2 + 1], 1, __ATOMIC_RELEASE,
                         __HIP_MEMORY_SCOPE_AGENT);
    } else {
      while (!__hip_atomic_load(&bar[idx * 2 + 1], __ATOMIC_ACQUIRE,
                                __HIP_MEMORY_SCOPE_AGENT))
        __builtin_amdgcn_s_sleep(2);
    }
    __threadfence();
  }
  __syncthreads();
}

// parallel (Hillis-Steele) descending-suffix scan of the 256-bucket histogram.
// Produces bst[v] = sum_{u>v} h[u], tb = max v with inclusive-suffix >= NSEL.
// Pure integer sums -> bit-identical across every block and phase.
__device__ __forceinline__ void prefix_scan(const int* __restrict__ hist, int b,
                                            int* h, int* suf, int* bst, int* tb_s) {
  int tid = threadIdx.x;
  int v = hist[b * 257 + tid];
  h[tid] = v;
  suf[tid] = v;
  if (tid == 0) *tb_s = 0;
  __syncthreads();
  for (int d = 1; d < 256; d <<= 1) {
    int add = (tid + d < 256) ? suf[tid + d] : 0;
    __syncthreads();
    suf[tid] += add;
    __syncthreads();
  }
  bst[tid] = suf[tid] - h[tid];
  if (suf[tid] >= NSEL && (tid == 255 || suf[tid + 1] < NSEL)) *tb_s = tid;
  __syncthreads();
}

#define SMEM_BYTES 25600

// MEGA kernel: phases {zero+hist} -> barrier -> {gather} -> barrier ->
// {sort+decode+bin} -> barrier -> {pairs}. 512 blocks = (batch b = bid>>6,
// sub = bid&63). Scores are cached in registers across the hist->gather
// barrier (probs read once). Replaces 4 kernel launches with 1.
__global__ __launch_bounds__(256, 4) void mega_kernel(
    const float* __restrict__ probs, int* __restrict__ hist,
    int* __restrict__ bfill, u64* __restrict__ cand,
    const float* __restrict__ anchors, const float* __restrict__ deltas,
    float4* __restrict__ boxes, int* __restrict__ cellCnt,
    u16* __restrict__ cellList, u16* __restrict__ largeList,
    u64* __restrict__ tileT, u32* __restrict__ sent, int* __restrict__ scnt,
    int* __restrict__ bar) {
  __shared__ __attribute__((aligned(16))) char smraw[SMEM_BYTES];
  int bid = blockIdx.x;
  int tid = threadIdx.x;
  int b = bid >> 6, sub = bid & 63;
  const float2* p2 = reinterpret_cast<const float2*>(probs);

  // ---- phase 0: zero tileT + histogram (scores cached in regs) ----
  for (size_t g = (size_t)bid * 256 + tid; g < (size_t)BATCH * NT * TILE * 4;
       g += (size_t)NBLK * 256)
    tileT[g] = 0ULL;
  int* h0 = (int*)smraw;  // [257]
  for (int i = tid; i < 257; i += 256) h0[i] = 0;
  __syncthreads();
  u32 cbits[8];
  int abase = sub * 2048;
#pragma unroll
  for (int k = 0; k < 8; ++k) {
    int a = abase + k * 256 + tid;
    u32 bits = __float_as_uint(p2[(size_t)b * NA + a].y);
    cbits[k] = bits;
    int bk = bucket_of(bits);
    atomicAdd(&h0[bk < 0 ? 256 : bk], 1);
  }
  __syncthreads();
  for (int i = tid; i < 257; i += 256)
    if (h0[i]) atomicAdd(&hist[b * 257 + i], h0[i]);
  grid_barrier(bar, 0);

  // ---- phase 1: gather (select + scatter candidate keys) ----
  {
    int* h = (int*)smraw;             // [256]
    int* suf = (int*)(smraw + 1024);  // [256]
    int* bst = (int*)(smraw + 2048);  // [256]
    int* tbp = (int*)(smraw + 3072);
    prefix_scan(hist, b, h, suf, bst, tbp);
    int tb = *tbp;
#pragma unroll
    for (int k = 0; k < 8; ++k) {
      u32 bits = cbits[k];
      int bk = bucket_of(bits);
      if (bk >= tb) {
        int a = abase + k * 256 + tid;
        int pos = bst[bk] + atomicAdd(&bfill[b * 257 + bk], 1);
        if (pos < CAND_CAP)
          cand[(size_t)b * CAND_CAP + pos] =
              ((u64)bits << 32) | (u64)(0xFFFFFFFFu - (u32)a);
      }
    }
  }
  grid_barrier(bar, 1);

  // ---- phase 2: per-bucket-slot bitonic sort + decode + clip + bin ----
  {
    int* h = (int*)smraw;
    int* suf = (int*)(smraw + 1024);
    int* bst = (int*)(smraw + 2048);
    int* tbp = (int*)(smraw + 3072);
    u64* s = (u64*)(smraw + 3088);  // [1024]
    prefix_scan(hist, b, h, suf, bst, tbp);
    int tb = *tbp;
    if (sub == 0) {
      float4 z = {0.f, 0.f, 0.f, 0.f};
      for (int r = NSEL + tid; r < NPAD; r += 256) boxes[(size_t)b * NPAD + r] = z;
    }
    int v = tb + sub;
    bool active = (v <= 255);
    int start = 0, cnt = 0;
    if (active) {
      start = bst[v];
      active = (start < NSEL);
    }
    if (active) {
      cnt = min(min(bfill[b * 257 + v], 1024), CAND_CAP - start);
      active = (cnt > 0);
    }
    if (active) {  // block-uniform
      const u64* seg = cand + (size_t)b * CAND_CAP + start;
      u64 x[4];
#pragma unroll
      for (int p = 0; p < 4; ++p) {
        int i = p * 256 + tid;
        x[p] = (i < cnt) ? seg[i] : 0ULL;
      }
      for (int k = 2; k <= 64; k <<= 1) {
        for (int j = k >> 1; j >= 1; j >>= 1) {
#pragma unroll
          for (int p = 0; p < 4; ++p) {
            int i = p * 256 + tid;
            u64 pv = shfl_xor_u64(x[p], j);
            bool takemax = (((i & j) == 0) == ((i & k) == 0));
            u64 mx = x[p] > pv ? x[p] : pv;
            u64 mn = x[p] < pv ? x[p] : pv;
            x[p] = takemax ? mx : mn;
          }
        }
      }
#pragma unroll
      for (int p = 0; p < 4; ++p) s[p * 256 + tid] = x[p];
      __syncthreads();
      for (int k = 128; k <= 1024; k <<= 1) {
        for (int j = k >> 1; j >= 64; j >>= 1) {
          for (int q = tid; q < 512; q += 256) {
            int i = ((q & ~(j - 1)) << 1) | (q & (j - 1));
            int ixj = i | j;
            u64 a = s[i], c = s[ixj];
            bool up = ((i & k) == 0);
            if (up ? (a < c) : (a > c)) { s[i] = c; s[ixj] = a; }
          }
          __syncthreads();
        }
#pragma unroll
        for (int p = 0; p < 4; ++p) x[p] = s[p * 256 + tid];
        for (int j = 32; j >= 1; j >>= 1) {
#pragma unroll
          for (int p = 0; p < 4; ++p) {
            int i = p * 256 + tid;
            u64 pv = shfl_xor_u64(x[p], j);
            bool takemax = (((i & j) == 0) == ((i & k) == 0));
            u64 mx = x[p] > pv ? x[p] : pv;
            u64 mn = x[p] < pv ? x[p] : pv;
            x[p] = takemax ? mx : mn;
          }
        }
        __syncthreads();
#pragma unroll
        for (int p = 0; p < 4; ++p) s[p * 256 + tid] = x[p];
        __syncthreads();
      }
      // decode + clip + bin ranks [start, start+cnt) ∩ [0, NSEL)
      for (int i = tid; i < cnt; i += 256) {
        int r = start + i;
        if (r >= NSEL) continue;
        u64 key = s[i];
        float4 o = {0.f, 0.f, 0.f, 0.f};
        u32 idx = 0xFFFFFFFFu - (u32)(key & 0xFFFFFFFFu);
        if (idx < NA) {
          float4 av = *reinterpret_cast<const float4*>(anchors + ((size_t)b * NA + idx) * 4);
          float4 dv = *reinterpret_cast<const float4*>(deltas + ((size_t)b * NA + idx) * 4);
          float y1 = av.x, x1 = av.y, y2 = av.z, x2 = av.w;
          float dy = dv.x * 0.1f, dx = dv.y * 0.1f;
          float dh = dv.z * 0.2f, dw = dv.w * 0.2f;
          float hh = y2 - y1, ww = x2 - x1;
          float cy = y1 + 0.5f * hh + dy * hh;
          float cx = x1 + 0.5f * ww + dx * ww;
          hh = hh * expf(dh);
          ww = ww * expf(dw);
          float ny1 = cy - 0.5f * hh, nx1 = cx - 0.5f * ww;
          float ny2 = ny1 + hh, nx2 = nx1 + ww;
          o.x = fminf(fmaxf(ny1, 0.f), 1.f);
          o.y = fminf(fmaxf(nx1, 0.f), 1.f);
          o.z = fminf(fmaxf(ny2, 0.f), 1.f);
          o.w = fminf(fmaxf(nx2, 0.f), 1.f);
        }
        boxes[(size_t)b * NPAD + r] = o;
        float bh = o.z - o.x, bw = o.w - o.y;
        if (bh > LTHR || bw > LTHR) {
          int pos = atomicAdd(&cellCnt[b * 65 + 64], 1);
          if (pos < LARGECAP) largeList[b * LARGECAP + pos] = (u16)r;
        } else {
          int gy = min(7, max(0, (int)((o.x + o.z) * 4.0f)));
          int gx = min(7, max(0, (int)((o.y + o.w) * 4.0f)));
          int cell = gy * 8 + gx;
          int pos = atomicAdd(&cellCnt[b * 65 + cell], 1);
          if (pos < CELLCAP) cellList[((size_t)b * 64 + cell) * CELLCAP + pos] = (u16)r;
        }
      }
    }
  }
  grid_barrier(bar, 2);

  // ---- phase 3: pairs (cell path for c=sub, then large path for lb=sub) ----
  {
    float4* Ab = (float4*)smraw;            // 4096
    float* Aa = (float*)(smraw + 4096);     // 1024
    float* Asx = (float*)(smraw + 5120);    // 1024  (x1+x2 = 2*cx)
    float* Asy = (float*)(smraw + 6144);    // 1024  (y1+y2 = 2*cy)
    u16* Ai = (u16*)(smraw + 7168);         // 512
    u16* fAi = (u16*)(smraw + 7680);        // 512
    float4* Bb = (float4*)(smraw + 8192);   // 12288
    float* Ba = (float*)(smraw + 20480);    // 3072
    u16* Bi = (u16*)(smraw + 23552);        // 1536
    int* nfA_s = (int*)(smraw + 25088);
    int* nfB_s = (int*)(smraw + 25092);

    int c = sub;
    int cy = c >> 3, cx = c & 7;
    int nA = min(cellCnt[b * 65 + c], CELLCAP);
    if (nA > 0) {
      for (int i = tid; i < nA; i += 256) {
        int r = cellList[((size_t)b * 64 + c) * CELLCAP + i];
        float4 bx = boxes[(size_t)b * NPAD + r];
        Ab[i] = bx;
        Aa[i] = (bx.z - bx.x) * (bx.w - bx.y);
        Asy[i] = bx.x + bx.z;
        Asx[i] = bx.y + bx.w;
        Ai[i] = (u16)r;
      }
      __syncthreads();
      // self pairs: exact triangular enumeration
      {
        int totS = (nA * (nA - 1)) >> 1;
        for (int t = tid; t < totS; t += 256) {
          int i = (int)((1.0f + sqrtf(8.0f * (float)t + 1.0f)) * 0.5f);
          int tri = (i * (i - 1)) >> 1;
          if (t < tri) {
            --i;
            tri = (i * (i - 1)) >> 1;
          } else if (t >= tri + i) {
            tri += i;
            ++i;
          }
          int j = t - tri;
          if (iou_gt(Ab[i], Ab[j], Aa[i], Aa[j]))
            emit_pair(b, Ai[i], Ai[j], tileT, sent, scnt);
        }
      }
      // phase R: right neighbor, x boundary band
      if (cx < 7) {
        __syncthreads();
        if (tid == 0) { *nfA_s = 0; *nfB_s = 0; }
        __syncthreads();
        float XR2 = (float)(cx + 1) * 0.25f;
        for (int i = tid; i < nA; i += 256)
          if (Asx[i] > XR2 - 0.078f) fAi[atomicAdd(nfA_s, 1)] = (u16)i;
        int nc = c + 1;
        int nN = min(cellCnt[b * 65 + nc], CELLCAP);
        for (int i = tid; i < nN; i += 256) {
          int r = cellList[((size_t)b * 64 + nc) * CELLCAP + i];
          float4 bx = boxes[(size_t)b * NPAD + r];
          if (bx.y + bx.w < XR2 + 0.078f) {
            int p = atomicAdd(nfB_s, 1);
            Bb[p] = bx;
            Ba[p] = (bx.z - bx.x) * (bx.w - bx.y);
            Bi[p] = (u16)r;
          }
        }
        __syncthreads();
        int nfA = *nfA_s, nfB = *nfB_s;
        if (nfA && nfB) {
          int s = 1;
          while ((1 << s) < nfB) ++s;
          int tot = nfA << s, m = (1 << s) - 1;
          for (int t = tid; t < tot; t += 256) {
            int ii = fAi[t >> s], j = t & m;
            if (j < nfB && iou_gt(Ab[ii], Bb[j], Aa[ii], Ba[j]))
              emit_pair(b, Ai[ii], Bi[j], tileT, sent, scnt);
          }
        }
      }
      // phase D: three lower neighbors, y band (+x band for diagonals)
      if (cy < 7) {
        __syncthreads();
        if (tid == 0) { *nfA_s = 0; *nfB_s = 0; }
        __syncthreads();
        float YB2 = (float)(cy + 1) * 0.25f;
        float XL2 = (float)cx * 0.25f;
        float XR2 = (float)(cx + 1) * 0.25f;
        for (int i = tid; i < nA; i += 256)
          if (Asy[i] > YB2 - 0.078f) fAi[atomicAdd(nfA_s, 1)] = (u16)i;
        for (int k = 0; k < 3; ++k) {
          int nx = cx + k - 1;
          if (nx < 0 || nx > 7) continue;
          int nc = (cy + 1) * 8 + nx;
          int nN = min(cellCnt[b * 65 + nc], CELLCAP);
          for (int i = tid; i < nN; i += 256) {
            int r = cellList[((size_t)b * 64 + nc) * CELLCAP + i];
            float4 bx = boxes[(size_t)b * NPAD + r];
            float bsy = bx.x + bx.z, bsx = bx.y + bx.w;
            bool ok = bsy < YB2 + 0.078f;
            if (k == 0) ok = ok && (bsx > XL2 - 0.078f);
            if (k == 2) ok = ok && (bsx < XR2 + 0.078f);
            if (ok) {
              int p = atomicAdd(nfB_s, 1);
              Bb[p] = bx;
              Ba[p] = (bx.z - bx.x) * (bx.w - bx.y);
              Bi[p] = (u16)r;
            }
          }
        }
        __syncthreads();
        int nfA = *nfA_s, nfB = *nfB_s;
        if (nfA && nfB) {
          int s = 1;
          while ((1 << s) < nfB) ++s;
          int tot = nfA << s, m = (1 << s) - 1;
          for (int t = tid; t < tot; t += 256) {
            int ii = fAi[t >> s], j = t & m;
            if (j < nfB && iou_gt(Ab[ii], Bb[j], Aa[ii], Ba[j]))
              emit_pair(b, Ai[ii], Bi[j], tileT, sent, scnt);
          }
        }
      }
    }
    // large path: lb = sub (window tests + large-large)
    int nL = min(cellCnt[b * 65 + 64], LARGECAP);
    if (nL > 0) {
      for (int li = sub; li < nL; li += 64) {
        int L = largeList[b * LARGECAP + li];
        float4 Lb = boxes[(size_t)b * NPAD + L];
        float hL = Lb.z - Lb.x, wL = Lb.w - Lb.y;
        if (0.7f * hL >= 0.126f || 0.7f * wL >= 0.126f) continue;
        float La = hL * wL;
        float sLy = Lb.x + Lb.z, sLx = Lb.y + Lb.w;
        int gy0 = max(0, (int)((sLy - 0.08f) * 4.0f));
        int gy1 = min(7, (int)((sLy + 0.08f) * 4.0f));
        int gx0 = max(0, (int)((sLx - 0.08f) * 4.0f));
        int gx1 = min(7, (int)((sLx + 0.08f) * 4.0f));
        for (int gy = gy0; gy <= gy1; ++gy)
          for (int gx = gx0; gx <= gx1; ++gx) {
            int cc = gy * 8 + gx;
            int cnt2 = min(cellCnt[b * 65 + cc], CELLCAP);
            for (int i = tid; i < cnt2; i += 256) {
              int r = cellList[((size_t)b * 64 + cc) * CELLCAP + i];
              float4 jb = boxes[(size_t)b * NPAD + r];
              float ja = (jb.z - jb.x) * (jb.w - jb.y);
              if (iou_gt(Lb, jb, La, ja)) emit_pair(b, L, r, tileT, sent, scnt);
            }
          }
      }
      int s = 1;
      while ((1 << s) < nL) ++s;
      int tot = nL << s, m = (1 << s) - 1;
      int stride = 64 * 256;
      for (int t = sub * 256 + tid; t < tot; t += stride) {
        int i = t >> s, j = t & m;
        if (j >= nL || i >= j) continue;
        int Li = largeList[b * LARGECAP + i];
        int Lj = largeList[b * LARGECAP + j];
        float4 A = boxes[(size_t)b * NPAD + Li];
        float4 B = boxes[(size_t)b * NPAD + Lj];
        float aA = (A.z - A.x) * (A.w - A.y);
        float aB = (B.z - B.x) * (B.w - B.y);
        if (iou_gt(A, B, aA, aB)) emit_pair(b, Li, Lj, tileT, sent, scnt);
      }
    }
  }
}

// K5: greedy NMS, 256-box TILE scan (unchanged from round 4).
__global__ __launch_bounds__(512) void nms_kernel(const u32* __restrict__ sent,
                                                  const int* __restrict__ scnt,
                                                  const u64* __restrict__ tileT,
                                                  const float4* __restrict__ boxes,
                                                  float4* __restrict__ out) {
  int b = blockIdx.x;
  int tid = threadIdx.x;
  int lane = tid & 63;
  int wv = tid >> 6;
  __shared__ u32 entS[LDSE];        // 49152 B
  __shared__ u32 rmb[TILE];         // 1024 B
  __shared__ u64 Kall[NWORD];       // 768 B
  __shared__ int cw[NT];
  __shared__ int prefix[NT + 1];
  __shared__ int baseT[NT];
  if (tid < NT) cw[tid] = min(scnt[b * NT + tid], SCAP);
  if (tid < TILE) rmb[tid] = 0u;
  if (tid < NWORD) Kall[tid] = 0ULL;
  {
    float4 z = {0.f, 0.f, 0.f, 0.f};
    for (int i = tid; i < PROP; i += 512) out[(size_t)b * PROP + i] = z;
  }
  __syncthreads();
  if (tid == 0) {
    int run = 0;
    for (int t = 0; t < NT; ++t) { prefix[t] = run; run += cw[t]; }
    prefix[NT] = run;
  }
  __syncthreads();
  for (int t = wv; t < NT; t += 8) {
    const u32* gb = sent + (size_t)(b * NT + t) * SCAP;
    int base = prefix[t], n = cw[t];
    for (int e = lane; e < n; e += 64) {
      int slot = base + e;
      if (slot < LDSE) entS[slot] = gb[e];
    }
  }
  __syncthreads();
  if (wv == 0) {
    const u64* tb0 = tileT + (size_t)b * (NT * TILE * 4);
    u64 mc[4][4], mn[4][4];
#pragma unroll
    for (int q = 0; q < 4; ++q)
#pragma unroll
      for (int j = 0; j < 4; ++j)
        mc[q][j] = tb0[(size_t)(q * 64 + lane) * 4 + j];
    int total = 0;
    for (int t = 0; t < NT; ++t) {
      if (t + 1 < NT) {
        const u64* nb = tb0 + (size_t)(t + 1) * (TILE * 4);
#pragma unroll
        for (int q = 0; q < 4; ++q)
#pragma unroll
          for (int j = 0; j < 4; ++j)
            mn[q][j] = nb[(size_t)(q * 64 + lane) * 4 + j];
      }
      {
        int n = cw[t], base = prefix[t];
        for (int e = lane; e < n; e += 64) {
          int slot = base + e;
          u32 ent = (slot < LDSE) ? entS[slot] : sent[(size_t)(b * NT + t) * SCAP + e];
          int srcr = (int)(ent >> 8);
          if ((Kall[srcr >> 6] >> (srcr & 63)) & 1ULL) rmb[ent & 255] = 1u;
        }
      }
      u32 f0 = rmb[lane], f1 = rmb[64 + lane], f2 = rmb[128 + lane], f3 = rmb[192 + lane];
      rmb[lane] = 0u;
      rmb[64 + lane] = 0u;
      rmb[128 + lane] = 0u;
      rmb[192 + lane] = 0u;
      int gw = t * 4;
      u64 K0, K1, K2, K3;
      {
        bool alive0 = (f0 == 0u) && ((valid_mask(gw) >> lane) & 1ULL);
        u64 cm = mc[0][0];
        u64 K = __ballot(alive0);
        for (int it = 0; it < 70; ++it) {
          bool alive = alive0 && ((K & cm) == 0ULL);
          u64 Kn = __ballot(alive);
          if (Kn == K) break;
          K = Kn;
        }
        K0 = K;
      }
      {
        u64 pre = K0 & mc[1][0];
        bool alive0 = (f1 == 0u) && ((valid_mask(gw + 1) >> lane) & 1ULL) && (pre == 0ULL);
        u64 cm = mc[1][1];
        u64 K = __ballot(alive0);
        for (int it = 0; it < 70; ++it) {
          bool alive = alive0 && ((K & cm) == 0ULL);
          u64 Kn = __ballot(alive);
          if (Kn == K) break;
          K = Kn;
        }
        K1 = K;
      }
      {
        u64 pre = (K0 & mc[2][0]) | (K1 & mc[2][1]);
        bool alive0 = (f2 == 0u) && ((valid_mask(gw + 2) >> lane) & 1ULL) && (pre == 0ULL);
        u64 cm = mc[2][2];
        u64 K = __ballot(alive0);
        for (int it = 0; it < 70; ++it) {
          bool alive = alive0 && ((K & cm) == 0ULL);
          u64 Kn = __ballot(alive);
          if (Kn == K) break;
          K = Kn;
        }
        K2 = K;
      }
      {
        u64 pre = (K0 & mc[3][0]) | (K1 & mc[3][1]) | (K2 & mc[3][2]);
        bool alive0 = (f3 == 0u) && ((valid_mask(gw + 3) >> lane) & 1ULL) && (pre == 0ULL);
        u64 cm = mc[3][3];
        u64 K = __ballot(alive0);
        for (int it = 0; it < 70; ++it) {
          bool alive = alive0 && ((K & cm) == 0ULL);
          u64 Kn = __ballot(alive);
          if (Kn == K) break;
          K = Kn;
        }
        K3 = K;
      }
      if (lane == 0) {
        Kall[gw] = K0;
        Kall[gw + 1] = K1;
        Kall[gw + 2] = K2;
        Kall[gw + 3] = K3;
        baseT[t] = total;
      }
      total += __popcll(K0) + __popcll(K1) + __popcll(K2) + __popcll(K3);
#pragma unroll
      for (int q = 0; q < 4; ++q)
#pragma unroll
        for (int j = 0; j < 4; ++j)
          mc[q][j] = mn[q][j];
    }
  }
  __syncthreads();
  for (int i = tid; i < NSEL; i += 512) {
    int g = i >> 6, bb = i & 63;
    u64 K = Kall[g];
    if ((K >> bb) & 1ULL) {
      int t = i >> 8;
      int rank = baseT[t];
      for (int q = t * 4; q < g; ++q) rank += __popcll(Kall[q]);
      rank += __popcll(K & ((1ULL << bb) - 1ULL));
      if (rank < PROP) out[(size_t)b * PROP + rank] = boxes[(size_t)b * NPAD + i];
    }
  }
}

extern "C" void kernel_launch(void* const* d_in, const int* in_sizes, int n_in,
                              void* d_out, int out_size, void* d_ws, size_t ws_size,
                              hipStream_t stream) {
  const float* probs = (const float*)d_in[0];    // (8,131072,2)
  const float* deltas = (const float*)d_in[1];   // (8,131072,4)
  const float* anchors = (const float*)d_in[2];  // (8,131072,4)
  char* ws = (char*)d_ws;
  int* hist = (int*)(ws + OFF_HIST);
  int* bfill = (int*)(ws + OFF_BFILL);
  int* scnt = (int*)(ws + OFF_SCNT);
  int* cellCnt = (int*)(ws + OFF_CELLCNT);
  int* bar = (int*)(ws + OFF_BAR);
  u64* tileT = (u64*)(ws + OFF_TILET);
  u64* cand = (u64*)(ws + OFF_CAND);
  float4* boxes = (float4*)(ws + OFF_BOXES);
  u16* cellList = (u16*)(ws + OFF_CELLLIST);
  u16* largeList = (u16*)(ws + OFF_LARGE);
  u32* sent = (u32*)(ws + OFF_SENT);

  (void)hipMemsetAsync(ws, 0, MEMSET_BYTES, stream);

  mega_kernel<<<NBLK, 256, 0, stream>>>(probs, hist, bfill, cand, anchors, deltas,
                                        boxes, cellCnt, cellList, largeList, tileT,
                                        sent, scnt, bar);
  nms_kernel<<<BATCH, 512, 0, stream>>>(sent, scnt, tileT, boxes, (float4*)d_out);
}

// Round 6
// 237.046 us; speedup vs baseline: 1.5972x; 1.5972x over previous
//
#include <hip/hip_runtime.h>

#pragma clang fp contract(off)

typedef unsigned long long u64;
typedef unsigned int u32;
typedef unsigned short u16;

#define BATCH 8
#define NA 131072
#define NSEL 6000
#define NT 24                 // 256-box tiles
#define TILE 256
#define NWORD (NT * 4)        // 96 64-bit words
#define NPAD (NT * TILE)      // 6144
#define CAND_CAP 8192
#define PROP 1000
#define SCAP 4096             // cross-tile entries cap per (batch, DEST tile)
#define LDSE 12288            // entries staged in LDS (u32 each)
#define CELLCAP 256           // boxes per 8x8 grid cell (mean ~94)
#define LARGECAP 1024         // "large" boxes per batch (dim > 1/8)
#define LTHR 0.125f
#define NBLK 512              // mega kernel grid; co-residency capacity >= 1024

// ---- workspace layout (bytes); [0, MEMSET_BYTES) zeroed every launch ----
#define OFF_HIST     0            // BATCH*257*4 = 8224
#define OFF_BFILL    8256         // 8224 -> 16480
#define OFF_SCNT     16512        // BATCH*NT*4 = 768 -> 17280
#define OFF_CELLCNT  17344        // 2080 -> 19424
#define OFF_BAR      19456        // 3*BATCH*64 ints = 6144 -> 25600
#define MEMSET_BYTES 25600
#define OFF_TILET    25600        // BATCH*NT*256*4*8 = 1572864 -> 1598464
#define OFF_CAND     1598464      // BATCH*8192*8 = 524288 -> 2122752
#define OFF_BOXES    2122752      // BATCH*6144*16 = 786432 -> 2909184
#define OFF_CELLLIST 2909184      // 262144 -> 3171328
#define OFF_LARGE    3171328      // 16384 -> 3187712
#define OFF_SENT     3187712      // BATCH*NT*SCAP*4 = 3145728 -> 6333440

__device__ __forceinline__ int bucket_of(u32 bits) {
  u32 hi = bits >> 16;
  if (hi >= 0x3E80u && hi < 0x3F80u) return (int)(hi - 0x3E80u);
  if (hi >= 0x3F80u && hi < 0x8000u) return 255;
  return -1;
}

// "RN32(inter / max(uni,1e-12)) > 0.7f" without fp32 divide, bit-exact:
// M=0x1.666667p-1 is the 0.7f/nextafter midpoint; RN32(t)>0.7f <=> t>=M;
// a/b>=M <=> a>=M*b, exact in fp64 (25-bit x 24-bit product).
__device__ __forceinline__ bool iou_gt(float4 A, float4 B, float areaA, float areaB) {
  float iy = fminf(A.z, B.z) - fmaxf(A.x, B.x);
  float ix = fminf(A.w, B.w) - fmaxf(A.y, B.y);
  float inter = fmaxf(iy, 0.0f) * fmaxf(ix, 0.0f);
  float uni = (areaA + areaB) - inter;
  float uc = fmaxf(uni, 1e-12f);
  return (double)inter >= 0x1.666667p-1 * (double)uc;
}

// Within-tile pairs -> dense bit matrix tileT[b][t][dst&255][(src&255)>>6].
// Cross-tile pairs -> u32 entry (src<<8)|(dst&255) in segment (b, dst_tile).
__device__ __forceinline__ void emit_pair(int b, int ra, int rb, u64* tileT,
                                          u32* sent, int* scnt) {
  int src = min(ra, rb), dst = max(ra, rb);
  int tsrc = src >> 8, tdst = dst >> 8;
  if (tsrc == tdst) {
    atomicOr(&tileT[(((size_t)b * NT + tdst) * TILE + (dst & 255)) * 4 + ((src >> 6) & 3)],
             1ULL << (src & 63));
  } else {
    int e = atomicAdd(&scnt[b * NT + tdst], 1);
    if (e < SCAP)
      sent[(size_t)(b * NT + tdst) * SCAP + e] = ((u32)src << 8) | (u32)(dst & 255);
  }
}

__device__ __forceinline__ u64 shfl_xor_u64(u64 v, int lanemask) {
  u32 lo = (u32)v, hi = (u32)(v >> 32);
  lo = (u32)__shfl_xor((int)lo, lanemask);
  hi = (u32)__shfl_xor((int)hi, lanemask);
  return ((u64)hi << 32) | (u64)lo;
}

__device__ __forceinline__ u64 valid_mask(int g) {
  int lo = g * 64;
  if (lo + 64 <= NSEL) return ~0ULL;
  if (lo >= NSEL) return 0ULL;
  return (1ULL << (NSEL - lo)) - 1ULL;
}

// Per-BATCH single-use barrier across the batch's 64 blocks, contention-free:
// each block sets its OWN flag (one relaxed agent store; release via the
// preceding threadfence); wave 0 polls all 64 flags with RELAXED agent loads
// (lane l polls f[l]; sc1 scope bits give cross-XCD visibility with no
// per-poll invalidates), then one threadfence (acquire). Zero atomic RMWs.
__device__ __forceinline__ void batch_barrier(int* flags, int idx, int b, int sub) {
  __syncthreads();
  int tid = threadIdx.x;
  int* f = flags + (idx * BATCH + b) * 64;
  if (tid == 0) {
    __threadfence();
    __hip_atomic_store(&f[sub], 1, __ATOMIC_RELAXED, __HIP_MEMORY_SCOPE_AGENT);
  }
  if (tid < 64) {
    while (__hip_atomic_load(&f[tid], __ATOMIC_RELAXED,
                             __HIP_MEMORY_SCOPE_AGENT) == 0)
      __builtin_amdgcn_s_sleep(2);
    __threadfence();
  }
  __syncthreads();
}

// parallel (Hillis-Steele) descending-suffix scan of the 256-bucket histogram.
// Produces bst[v] = sum_{u>v} h[u], tb = max v with inclusive-suffix >= NSEL.
// Pure integer sums -> bit-identical across every block and phase.
__device__ __forceinline__ void prefix_scan(const int* __restrict__ hist, int b,
                                            int* h, int* suf, int* bst, int* tb_s) {
  int tid = threadIdx.x;
  int v = hist[b * 257 + tid];
  h[tid] = v;
  suf[tid] = v;
  if (tid == 0) *tb_s = 0;
  __syncthreads();
  for (int d = 1; d < 256; d <<= 1) {
    int add = (tid + d < 256) ? suf[tid + d] : 0;
    __syncthreads();
    suf[tid] += add;
    __syncthreads();
  }
  bst[tid] = suf[tid] - h[tid];
  if (suf[tid] >= NSEL && (tid == 255 || suf[tid + 1] < NSEL)) *tb_s = tid;
  __syncthreads();
}

#define SMEM_BYTES 25600

// MEGA kernel: per-batch phases {zero+hist} -> bar -> {gather} -> bar ->
// {sort+decode+bin} -> bar -> {pairs}. 512 blocks = (b = bid>>6, sub = bid&63).
// Scores cached in registers across the hist->gather barrier (probs read once).
__global__ __launch_bounds__(256, 4) void mega_kernel(
    const float* __restrict__ probs, int* __restrict__ hist,
    int* __restrict__ bfill, u64* __restrict__ cand,
    const float* __restrict__ anchors, const float* __restrict__ deltas,
    float4* __restrict__ boxes, int* __restrict__ cellCnt,
    u16* __restrict__ cellList, u16* __restrict__ largeList,
    u64* __restrict__ tileT, u32* __restrict__ sent, int* __restrict__ scnt,
    int* __restrict__ bar) {
  __shared__ __attribute__((aligned(16))) char smraw[SMEM_BYTES];
  int bid = blockIdx.x;
  int tid = threadIdx.x;
  int b = bid >> 6, sub = bid & 63;
  const float2* p2 = reinterpret_cast<const float2*>(probs);

  // ---- phase 0: zero this batch's tileT + histogram (scores cached) ----
  for (int g = sub * 256 + tid; g < NT * TILE * 4; g += 64 * 256)
    tileT[(size_t)b * (NT * TILE * 4) + g] = 0ULL;
  int* h0 = (int*)smraw;  // [257]
  for (int i = tid; i < 257; i += 256) h0[i] = 0;
  __syncthreads();
  u32 cbits[8];
  int abase = sub * 2048;
#pragma unroll
  for (int k = 0; k < 8; ++k) {
    int a = abase + k * 256 + tid;
    u32 bits = __float_as_uint(p2[(size_t)b * NA + a].y);
    cbits[k] = bits;
    int bk = bucket_of(bits);
    atomicAdd(&h0[bk < 0 ? 256 : bk], 1);
  }
  __syncthreads();
  for (int i = tid; i < 257; i += 256)
    if (h0[i]) atomicAdd(&hist[b * 257 + i], h0[i]);
  batch_barrier(bar, 0, b, sub);

  // ---- phase 1: gather (select + scatter candidate keys) ----
  {
    int* h = (int*)smraw;             // [256]
    int* suf = (int*)(smraw + 1024);  // [256]
    int* bst = (int*)(smraw + 2048);  // [256]
    int* tbp = (int*)(smraw + 3072);
    prefix_scan(hist, b, h, suf, bst, tbp);
    int tb = *tbp;
#pragma unroll
    for (int k = 0; k < 8; ++k) {
      u32 bits = cbits[k];
      int bk = bucket_of(bits);
      if (bk >= tb) {
        int a = abase + k * 256 + tid;
        int pos = bst[bk] + atomicAdd(&bfill[b * 257 + bk], 1);
        if (pos < CAND_CAP)
          cand[(size_t)b * CAND_CAP + pos] =
              ((u64)bits << 32) | (u64)(0xFFFFFFFFu - (u32)a);
      }
    }
  }
  batch_barrier(bar, 1, b, sub);

  // ---- phase 2: per-bucket-slot bitonic sort + decode + clip + bin ----
  {
    int* h = (int*)smraw;
    int* suf = (int*)(smraw + 1024);
    int* bst = (int*)(smraw + 2048);
    int* tbp = (int*)(smraw + 3072);
    u64* s = (u64*)(smraw + 3088);  // [1024]
    prefix_scan(hist, b, h, suf, bst, tbp);
    int tb = *tbp;
    if (sub == 0) {
      float4 z = {0.f, 0.f, 0.f, 0.f};
      for (int r = NSEL + tid; r < NPAD; r += 256) boxes[(size_t)b * NPAD + r] = z;
    }
    int v = tb + sub;
    bool active = (v <= 255);
    int start = 0, cnt = 0;
    if (active) {
      start = bst[v];
      active = (start < NSEL);
    }
    if (active) {
      cnt = min(min(bfill[b * 257 + v], 1024), CAND_CAP - start);
      active = (cnt > 0);
    }
    if (active) {  // block-uniform
      const u64* seg = cand + (size_t)b * CAND_CAP + start;
      u64 x[4];
#pragma unroll
      for (int p = 0; p < 4; ++p) {
        int i = p * 256 + tid;
        x[p] = (i < cnt) ? seg[i] : 0ULL;
      }
      for (int k = 2; k <= 64; k <<= 1) {
        for (int j = k >> 1; j >= 1; j >>= 1) {
#pragma unroll
          for (int p = 0; p < 4; ++p) {
            int i = p * 256 + tid;
            u64 pv = shfl_xor_u64(x[p], j);
            bool takemax = (((i & j) == 0) == ((i & k) == 0));
            u64 mx = x[p] > pv ? x[p] : pv;
            u64 mn = x[p] < pv ? x[p] : pv;
            x[p] = takemax ? mx : mn;
          }
        }
      }
#pragma unroll
      for (int p = 0; p < 4; ++p) s[p * 256 + tid] = x[p];
      __syncthreads();
      for (int k = 128; k <= 1024; k <<= 1) {
        for (int j = k >> 1; j >= 64; j >>= 1) {
          for (int q = tid; q < 512; q += 256) {
            int i = ((q & ~(j - 1)) << 1) | (q & (j - 1));
            int ixj = i | j;
            u64 a = s[i], c = s[ixj];
            bool up = ((i & k) == 0);
            if (up ? (a < c) : (a > c)) { s[i] = c; s[ixj] = a; }
          }
          __syncthreads();
        }
#pragma unroll
        for (int p = 0; p < 4; ++p) x[p] = s[p * 256 + tid];
        for (int j = 32; j >= 1; j >>= 1) {
#pragma unroll
          for (int p = 0; p < 4; ++p) {
            int i = p * 256 + tid;
            u64 pv = shfl_xor_u64(x[p], j);
            bool takemax = (((i & j) == 0) == ((i & k) == 0));
            u64 mx = x[p] > pv ? x[p] : pv;
            u64 mn = x[p] < pv ? x[p] : pv;
            x[p] = takemax ? mx : mn;
          }
        }
        __syncthreads();
#pragma unroll
        for (int p = 0; p < 4; ++p) s[p * 256 + tid] = x[p];
        __syncthreads();
      }
      // decode + clip + bin ranks [start, start+cnt) ∩ [0, NSEL)
      for (int i = tid; i < cnt; i += 256) {
        int r = start + i;
        if (r >= NSEL) continue;
        u64 key = s[i];
        float4 o = {0.f, 0.f, 0.f, 0.f};
        u32 idx = 0xFFFFFFFFu - (u32)(key & 0xFFFFFFFFu);
        if (idx < NA) {
          float4 av = *reinterpret_cast<const float4*>(anchors + ((size_t)b * NA + idx) * 4);
          float4 dv = *reinterpret_cast<const float4*>(deltas + ((size_t)b * NA + idx) * 4);
          float y1 = av.x, x1 = av.y, y2 = av.z, x2 = av.w;
          float dy = dv.x * 0.1f, dx = dv.y * 0.1f;
          float dh = dv.z * 0.2f, dw = dv.w * 0.2f;
          float hh = y2 - y1, ww = x2 - x1;
          float cy = y1 + 0.5f * hh + dy * hh;
          float cx = x1 + 0.5f * ww + dx * ww;
          hh = hh * expf(dh);
          ww = ww * expf(dw);
          float ny1 = cy - 0.5f * hh, nx1 = cx - 0.5f * ww;
          float ny2 = ny1 + hh, nx2 = nx1 + ww;
          o.x = fminf(fmaxf(ny1, 0.f), 1.f);
          o.y = fminf(fmaxf(nx1, 0.f), 1.f);
          o.z = fminf(fmaxf(ny2, 0.f), 1.f);
          o.w = fminf(fmaxf(nx2, 0.f), 1.f);
        }
        boxes[(size_t)b * NPAD + r] = o;
        float bh = o.z - o.x, bw = o.w - o.y;
        if (bh > LTHR || bw > LTHR) {
          int pos = atomicAdd(&cellCnt[b * 65 + 64], 1);
          if (pos < LARGECAP) largeList[b * LARGECAP + pos] = (u16)r;
        } else {
          int gy = min(7, max(0, (int)((o.x + o.z) * 4.0f)));
          int gx = min(7, max(0, (int)((o.y + o.w) * 4.0f)));
          int cell = gy * 8 + gx;
          int pos = atomicAdd(&cellCnt[b * 65 + cell], 1);
          if (pos < CELLCAP) cellList[((size_t)b * 64 + cell) * CELLCAP + pos] = (u16)r;
        }
      }
    }
  }
  batch_barrier(bar, 2, b, sub);

  // ---- phase 3: pairs (cell path for c=sub, then large path for lb=sub) ----
  {
    float4* Ab = (float4*)smraw;            // 4096
    float* Aa = (float*)(smraw + 4096);     // 1024
    float* Asx = (float*)(smraw + 5120);    // 1024  (x1+x2 = 2*cx)
    float* Asy = (float*)(smraw + 6144);    // 1024  (y1+y2 = 2*cy)
    u16* Ai = (u16*)(smraw + 7168);         // 512
    u16* fAi = (u16*)(smraw + 7680);        // 512
    float4* Bb = (float4*)(smraw + 8192);   // 12288
    float* Ba = (float*)(smraw + 20480);    // 3072
    u16* Bi = (u16*)(smraw + 23552);        // 1536
    int* nfA_s = (int*)(smraw + 25088);
    int* nfB_s = (int*)(smraw + 25092);

    int c = sub;
    int cy = c >> 3, cx = c & 7;
    int nA = min(cellCnt[b * 65 + c], CELLCAP);
    if (nA > 0) {
      for (int i = tid; i < nA; i += 256) {
        int r = cellList[((size_t)b * 64 + c) * CELLCAP + i];
        float4 bx = boxes[(size_t)b * NPAD + r];
        Ab[i] = bx;
        Aa[i] = (bx.z - bx.x) * (bx.w - bx.y);
        Asy[i] = bx.x + bx.z;
        Asx[i] = bx.y + bx.w;
        Ai[i] = (u16)r;
      }
      __syncthreads();
      // self pairs: exact triangular enumeration
      {
        int totS = (nA * (nA - 1)) >> 1;
        for (int t = tid; t < totS; t += 256) {
          int i = (int)((1.0f + sqrtf(8.0f * (float)t + 1.0f)) * 0.5f);
          int tri = (i * (i - 1)) >> 1;
          if (t < tri) {
            --i;
            tri = (i * (i - 1)) >> 1;
          } else if (t >= tri + i) {
            tri += i;
            ++i;
          }
          int j = t - tri;
          if (iou_gt(Ab[i], Ab[j], Aa[i], Aa[j]))
            emit_pair(b, Ai[i], Ai[j], tileT, sent, scnt);
        }
      }
      // phase R: right neighbor, x boundary band
      if (cx < 7) {
        __syncthreads();
        if (tid == 0) { *nfA_s = 0; *nfB_s = 0; }
        __syncthreads();
        float XR2 = (float)(cx + 1) * 0.25f;
        for (int i = tid; i < nA; i += 256)
          if (Asx[i] > XR2 - 0.078f) fAi[atomicAdd(nfA_s, 1)] = (u16)i;
        int nc = c + 1;
        int nN = min(cellCnt[b * 65 + nc], CELLCAP);
        for (int i = tid; i < nN; i += 256) {
          int r = cellList[((size_t)b * 64 + nc) * CELLCAP + i];
          float4 bx = boxes[(size_t)b * NPAD + r];
          if (bx.y + bx.w < XR2 + 0.078f) {
            int p = atomicAdd(nfB_s, 1);
            Bb[p] = bx;
            Ba[p] = (bx.z - bx.x) * (bx.w - bx.y);
            Bi[p] = (u16)r;
          }
        }
        __syncthreads();
        int nfA = *nfA_s, nfB = *nfB_s;
        if (nfA && nfB) {
          int s = 1;
          while ((1 << s) < nfB) ++s;
          int tot = nfA << s, m = (1 << s) - 1;
          for (int t = tid; t < tot; t += 256) {
            int ii = fAi[t >> s], j = t & m;
            if (j < nfB && iou_gt(Ab[ii], Bb[j], Aa[ii], Ba[j]))
              emit_pair(b, Ai[ii], Bi[j], tileT, sent, scnt);
          }
        }
      }
      // phase D: three lower neighbors, y band (+x band for diagonals)
      if (cy < 7) {
        __syncthreads();
        if (tid == 0) { *nfA_s = 0; *nfB_s = 0; }
        __syncthreads();
        float YB2 = (float)(cy + 1) * 0.25f;
        float XL2 = (float)cx * 0.25f;
        float XR2 = (float)(cx + 1) * 0.25f;
        for (int i = tid; i < nA; i += 256)
          if (Asy[i] > YB2 - 0.078f) fAi[atomicAdd(nfA_s, 1)] = (u16)i;
        for (int k = 0; k < 3; ++k) {
          int nx = cx + k - 1;
          if (nx < 0 || nx > 7) continue;
          int nc = (cy + 1) * 8 + nx;
          int nN = min(cellCnt[b * 65 + nc], CELLCAP);
          for (int i = tid; i < nN; i += 256) {
            int r = cellList[((size_t)b * 64 + nc) * CELLCAP + i];
            float4 bx = boxes[(size_t)b * NPAD + r];
            float bsy = bx.x + bx.z, bsx = bx.y + bx.w;
            bool ok = bsy < YB2 + 0.078f;
            if (k == 0) ok = ok && (bsx > XL2 - 0.078f);
            if (k == 2) ok = ok && (bsx < XR2 + 0.078f);
            if (ok) {
              int p = atomicAdd(nfB_s, 1);
              Bb[p] = bx;
              Ba[p] = (bx.z - bx.x) * (bx.w - bx.y);
              Bi[p] = (u16)r;
            }
          }
        }
        __syncthreads();
        int nfA = *nfA_s, nfB = *nfB_s;
        if (nfA && nfB) {
          int s = 1;
          while ((1 << s) < nfB) ++s;
          int tot = nfA << s, m = (1 << s) - 1;
          for (int t = tid; t < tot; t += 256) {
            int ii = fAi[t >> s], j = t & m;
            if (j < nfB && iou_gt(Ab[ii], Bb[j], Aa[ii], Ba[j]))
              emit_pair(b, Ai[ii], Bi[j], tileT, sent, scnt);
          }
        }
      }
    }
    // large path: lb = sub (window tests + large-large)
    int nL = min(cellCnt[b * 65 + 64], LARGECAP);
    if (nL > 0) {
      for (int li = sub; li < nL; li += 64) {
        int L = largeList[b * LARGECAP + li];
        float4 Lb = boxes[(size_t)b * NPAD + L];
        float hL = Lb.z - Lb.x, wL = Lb.w - Lb.y;
        if (0.7f * hL >= 0.126f || 0.7f * wL >= 0.126f) continue;
        float La = hL * wL;
        float sLy = Lb.x + Lb.z, sLx = Lb.y + Lb.w;
        int gy0 = max(0, (int)((sLy - 0.08f) * 4.0f));
        int gy1 = min(7, (int)((sLy + 0.08f) * 4.0f));
        int gx0 = max(0, (int)((sLx - 0.08f) * 4.0f));
        int gx1 = min(7, (int)((sLx + 0.08f) * 4.0f));
        for (int gy = gy0; gy <= gy1; ++gy)
          for (int gx = gx0; gx <= gx1; ++gx) {
            int cc = gy * 8 + gx;
            int cnt2 = min(cellCnt[b * 65 + cc], CELLCAP);
            for (int i = tid; i < cnt2; i += 256) {
              int r = cellList[((size_t)b * 64 + cc) * CELLCAP + i];
              float4 jb = boxes[(size_t)b * NPAD + r];
              float ja = (jb.z - jb.x) * (jb.w - jb.y);
              if (iou_gt(Lb, jb, La, ja)) emit_pair(b, L, r, tileT, sent, scnt);
            }
          }
      }
      int s = 1;
      while ((1 << s) < nL) ++s;
      int tot = nL << s, m = (1 << s) - 1;
      int stride = 64 * 256;
      for (int t = sub * 256 + tid; t < tot; t += stride) {
        int i = t >> s, j = t & m;
        if (j >= nL || i >= j) continue;
        int Li = largeList[b * LARGECAP + i];
        int Lj = largeList[b * LARGECAP + j];
        float4 A = boxes[(size_t)b * NPAD + Li];
        float4 B = boxes[(size_t)b * NPAD + Lj];
        float aA = (A.z - A.x) * (A.w - A.y);
        float aB = (B.z - B.x) * (B.w - B.y);
        if (iou_gt(A, B, aA, aB)) emit_pair(b, Li, Lj, tileT, sent, scnt);
      }
    }
  }
}

// K5: greedy NMS, 256-box TILE scan (unchanged from round 4).
__global__ __launch_bounds__(512) void nms_kernel(const u32* __restrict__ sent,
                                                  const int* __restrict__ scnt,
                                                  const u64* __restrict__ tileT,
                                                  const float4* __restrict__ boxes,
                                                  float4* __restrict__ out) {
  int b = blockIdx.x;
  int tid = threadIdx.x;
  int lane = tid & 63;
  int wv = tid >> 6;
  __shared__ u32 entS[LDSE];        // 49152 B
  __shared__ u32 rmb[TILE];         // 1024 B
  __shared__ u64 Kall[NWORD];       // 768 B
  __shared__ int cw[NT];
  __shared__ int prefix[NT + 1];
  __shared__ int baseT[NT];
  if (tid < NT) cw[tid] = min(scnt[b * NT + tid], SCAP);
  if (tid < TILE) rmb[tid] = 0u;
  if (tid < NWORD) Kall[tid] = 0ULL;
  {
    float4 z = {0.f, 0.f, 0.f, 0.f};
    for (int i = tid; i < PROP; i += 512) out[(size_t)b * PROP + i] = z;
  }
  __syncthreads();
  if (tid == 0) {
    int run = 0;
    for (int t = 0; t < NT; ++t) { prefix[t] = run; run += cw[t]; }
    prefix[NT] = run;
  }
  __syncthreads();
  for (int t = wv; t < NT; t += 8) {
    const u32* gb = sent + (size_t)(b * NT + t) * SCAP;
    int base = prefix[t], n = cw[t];
    for (int e = lane; e < n; e += 64) {
      int slot = base + e;
      if (slot < LDSE) entS[slot] = gb[e];
    }
  }
  __syncthreads();
  if (wv == 0) {
    const u64* tb0 = tileT + (size_t)b * (NT * TILE * 4);
    u64 mc[4][4], mn[4][4];
#pragma unroll
    for (int q = 0; q < 4; ++q)
#pragma unroll
      for (int j = 0; j < 4; ++j)
        mc[q][j] = tb0[(size_t)(q * 64 + lane) * 4 + j];
    int total = 0;
    for (int t = 0; t < NT; ++t) {
      if (t + 1 < NT) {
        const u64* nb = tb0 + (size_t)(t + 1) * (TILE * 4);
#pragma unroll
        for (int q = 0; q < 4; ++q)
#pragma unroll
          for (int j = 0; j < 4; ++j)
            mn[q][j] = nb[(size_t)(q * 64 + lane) * 4 + j];
      }
      {
        int n = cw[t], base = prefix[t];
        for (int e = lane; e < n; e += 64) {
          int slot = base + e;
          u32 ent = (slot < LDSE) ? entS[slot] : sent[(size_t)(b * NT + t) * SCAP + e];
          int srcr = (int)(ent >> 8);
          if ((Kall[srcr >> 6] >> (srcr & 63)) & 1ULL) rmb[ent & 255] = 1u;
        }
      }
      u32 f0 = rmb[lane], f1 = rmb[64 + lane], f2 = rmb[128 + lane], f3 = rmb[192 + lane];
      rmb[lane] = 0u;
      rmb[64 + lane] = 0u;
      rmb[128 + lane] = 0u;
      rmb[192 + lane] = 0u;
      int gw = t * 4;
      u64 K0, K1, K2, K3;
      {
        bool alive0 = (f0 == 0u) && ((valid_mask(gw) >> lane) & 1ULL);
        u64 cm = mc[0][0];
        u64 K = __ballot(alive0);
        for (int it = 0; it < 70; ++it) {
          bool alive = alive0 && ((K & cm) == 0ULL);
          u64 Kn = __ballot(alive);
          if (Kn == K) break;
          K = Kn;
        }
        K0 = K;
      }
      {
        u64 pre = K0 & mc[1][0];
        bool alive0 = (f1 == 0u) && ((valid_mask(gw + 1) >> lane) & 1ULL) && (pre == 0ULL);
        u64 cm = mc[1][1];
        u64 K = __ballot(alive0);
        for (int it = 0; it < 70; ++it) {
          bool alive = alive0 && ((K & cm) == 0ULL);
          u64 Kn = __ballot(alive);
          if (Kn == K) break;
          K = Kn;
        }
        K1 = K;
      }
      {
        u64 pre = (K0 & mc[2][0]) | (K1 & mc[2][1]);
        bool alive0 = (f2 == 0u) && ((valid_mask(gw + 2) >> lane) & 1ULL) && (pre == 0ULL);
        u64 cm = mc[2][2];
        u64 K = __ballot(alive0);
        for (int it = 0; it < 70; ++it) {
          bool alive = alive0 && ((K & cm) == 0ULL);
          u64 Kn = __ballot(alive);
          if (Kn == K) break;
          K = Kn;
        }
        K2 = K;
      }
      {
        u64 pre = (K0 & mc[3][0]) | (K1 & mc[3][1]) | (K2 & mc[3][2]);
        bool alive0 = (f3 == 0u) && ((valid_mask(gw + 3) >> lane) & 1ULL) && (pre == 0ULL);
        u64 cm = mc[3][3];
        u64 K = __ballot(alive0);
        for (int it = 0; it < 70; ++it) {
          bool alive = alive0 && ((K & cm) == 0ULL);
          u64 Kn = __ballot(alive);
          if (Kn == K) break;
          K = Kn;
        }
        K3 = K;
      }
      if (lane == 0) {
        Kall[gw] = K0;
        Kall[gw + 1] = K1;
        Kall[gw + 2] = K2;
        Kall[gw + 3] = K3;
        baseT[t] = total;
      }
      total += __popcll(K0) + __popcll(K1) + __popcll(K2) + __popcll(K3);
#pragma unroll
      for (int q = 0; q < 4; ++q)
#pragma unroll
        for (int j = 0; j < 4; ++j)
          mc[q][j] = mn[q][j];
    }
  }
  __syncthreads();
  for (int i = tid; i < NSEL; i += 512) {
    int g = i >> 6, bb = i & 63;
    u64 K = Kall[g];
    if ((K >> bb) & 1ULL) {
      int t = i >> 8;
      int rank = baseT[t];
      for (int q = t * 4; q < g; ++q) rank += __popcll(Kall[q]);
      rank += __popcll(K & ((1ULL << bb) - 1ULL));
      if (rank < PROP) out[(size_t)b * PROP + rank] = boxes[(size_t)b * NPAD + i];
    }
  }
}

extern "C" void kernel_launch(void* const* d_in, const int* in_sizes, int n_in,
                              void* d_out, int out_size, void* d_ws, size_t ws_size,
                              hipStream_t stream) {
  const float* probs = (const float*)d_in[0];    // (8,131072,2)
  const float* deltas = (const float*)d_in[1];   // (8,131072,4)
  const float* anchors = (const float*)d_in[2];  // (8,131072,4)
  char* ws = (char*)d_ws;
  int* hist = (int*)(ws + OFF_HIST);
  int* bfill = (int*)(ws + OFF_BFILL);
  int* scnt = (int*)(ws + OFF_SCNT);
  int* cellCnt = (int*)(ws + OFF_CELLCNT);
  int* bar = (int*)(ws + OFF_BAR);
  u64* tileT = (u64*)(ws + OFF_TILET);
  u64* cand = (u64*)(ws + OFF_CAND);
  float4* boxes = (float4*)(ws + OFF_BOXES);
  u16* cellList = (u16*)(ws + OFF_CELLLIST);
  u16* largeList = (u16*)(ws + OFF_LARGE);
  u32* sent = (u32*)(ws + OFF_SENT);

  (void)hipMemsetAsync(ws, 0, MEMSET_BYTES, stream);

  mega_kernel<<<NBLK, 256, 0, stream>>>(probs, hist, bfill, cand, anchors, deltas,
                                        boxes, cellCnt, cellList, largeList, tileT,
                                        sent, scnt, bar);
  nms_kernel<<<BATCH, 512, 0, stream>>>(sent, scnt, tileT, boxes, (float4*)d_out);
}

// Round 7
// 219.260 us; speedup vs baseline: 1.7267x; 1.0811x over previous
//
#include <hip/hip_runtime.h>

#pragma clang fp contract(off)

typedef unsigned long long u64;
typedef unsigned int u32;
typedef unsigned short u16;

#define BATCH 8
#define NA 131072
#define NSEL 6000
#define NT 24                 // 256-box tiles
#define TILE 256
#define NWORD (NT * 4)        // 96 64-bit words
#define NPAD (NT * TILE)      // 6144
#define CAND_CAP 8192
#define PROP 1000
#define SCAP 4096             // cross-tile entries cap per (batch, DEST tile)
#define LDSE 12288            // entries staged in LDS (u32 each)
#define CELLCAP 256           // boxes per 8x8 grid cell (mean ~94)
#define LARGECAP 1024         // "large" boxes per batch (dim > 1/8)
#define LTHR 0.125f

// ---- workspace layout (bytes); NOTHING is pre-zeroed by the host ----
// histPB rows are fully overwritten each launch (per-block, non-atomic);
// bfill/scnt/cellCnt are zeroed by hist_kernel block 0 of each batch
// (launch boundary orders them before their consumers); tileT is zeroed
// inside sortdecode_kernel; cand/sent/boxes are bounds-guarded.
#define OFF_HISTPB   0            // BATCH*64*256*4 = 524288
#define OFF_BFILL    524288       // BATCH*257*4 = 8224 -> 532512 (pad 532544)
#define OFF_SCNT     532544       // BATCH*NT*4 = 768 -> 533312 (pad 533376)
#define OFF_CELLCNT  533376       // BATCH*65*4 = 2080 -> 535456 (pad 535488)
#define OFF_TILET    535488       // BATCH*NT*256*4*8 = 1572864 -> 2108352
#define OFF_CAND     2108352      // BATCH*8192*8 = 524288 -> 2632640
#define OFF_BOXES    2632640      // BATCH*6144*16 = 786432 -> 3419072
#define OFF_CELLLIST 3419072      // 262144 -> 3681216
#define OFF_LARGE    3681216      // 16384 -> 3697600
#define OFF_SENT     3697600      // BATCH*NT*SCAP*4 = 3145728 -> 6843328

__device__ __forceinline__ int bucket_of(u32 bits) {
  u32 hi = bits >> 16;
  if (hi >= 0x3E80u && hi < 0x3F80u) return (int)(hi - 0x3E80u);
  if (hi >= 0x3F80u && hi < 0x8000u) return 255;
  return -1;
}

// "RN32(inter / max(uni,1e-12)) > 0.7f" without fp32 divide, bit-exact:
// M=0x1.666667p-1 is the 0.7f/nextafter midpoint; RN32(t)>0.7f <=> t>=M;
// a/b>=M <=> a>=M*b, exact in fp64 (25-bit x 24-bit product).
__device__ __forceinline__ bool iou_gt(float4 A, float4 B, float areaA, float areaB) {
  float iy = fminf(A.z, B.z) - fmaxf(A.x, B.x);
  float ix = fminf(A.w, B.w) - fmaxf(A.y, B.y);
  float inter = fmaxf(iy, 0.0f) * fmaxf(ix, 0.0f);
  float uni = (areaA + areaB) - inter;
  float uc = fmaxf(uni, 1e-12f);
  return (double)inter >= 0x1.666667p-1 * (double)uc;
}

// Within-tile pairs -> dense bit matrix tileT[b][t][dst&255][(src&255)>>6].
// Cross-tile pairs -> u32 entry (src<<8)|(dst&255) in segment (b, dst_tile).
__device__ __forceinline__ void emit_pair(int b, int ra, int rb, u64* tileT,
                                          u32* sent, int* scnt) {
  int src = min(ra, rb), dst = max(ra, rb);
  int tsrc = src >> 8, tdst = dst >> 8;
  if (tsrc == tdst) {
    atomicOr(&tileT[(((size_t)b * NT + tdst) * TILE + (dst & 255)) * 4 + ((src >> 6) & 3)],
             1ULL << (src & 63));
  } else {
    int e = atomicAdd(&scnt[b * NT + tdst], 1);
    if (e < SCAP)
      sent[(size_t)(b * NT + tdst) * SCAP + e] = ((u32)src << 8) | (u32)(dst & 255);
  }
}

__device__ __forceinline__ u64 shfl_xor_u64(u64 v, int lanemask) {
  u32 lo = (u32)v, hi = (u32)(v >> 32);
  lo = (u32)__shfl_xor((int)lo, lanemask);
  hi = (u32)__shfl_xor((int)hi, lanemask);
  return ((u64)hi << 32) | (u64)lo;
}

__device__ __forceinline__ u64 valid_mask(int g) {
  int lo = g * 64;
  if (lo + 64 <= NSEL) return ~0ULL;
  if (lo >= NSEL) return 0ULL;
  return (1ULL << (NSEL - lo)) - 1ULL;
}

// compute tbuck + descending bucket prefix from the 64 per-block histogram
// rows (summed here; rows were fully overwritten by hist_kernel, no zeroing).
// Pure integer sums -> bit-identical across every block.
__device__ __forceinline__ void prefix_from_hist(const int* __restrict__ histPB,
                                                 int b, int* h, int* bst,
                                                 int* tb_s) {
  int tid = threadIdx.x;
  {
    const int* hp = histPB + (size_t)b * 64 * 256 + tid;
    int acc = 0;
#pragma unroll 8
    for (int k = 0; k < 64; ++k) acc += hp[k * 256];
    h[tid] = acc;
  }
  __syncthreads();
  if (tid == 0) {
    int run = 0, t = 0;
    bool found = false;
    for (int v = 255; v >= 0; --v) {
      bst[v] = run;
      run += h[v];
      if (!found && run >= NSEL) { t = v; found = true; }
    }
    *tb_s = t;
  }
  __syncthreads();
}

// K1: per-batch per-BLOCK 256-bucket histogram (non-atomic global write).
// Block 0 of each batch also zeroes bfill/scnt/cellCnt (consumed only by
// later kernels -> ordered by launch boundary). Replaces the host memset.
__global__ __launch_bounds__(256) void hist_kernel(const float* __restrict__ probs,
                                                   int* __restrict__ histPB,
                                                   int* __restrict__ bfill,
                                                   int* __restrict__ scnt,
                                                   int* __restrict__ cellCnt) {
  int b = blockIdx.y;
  int bx = blockIdx.x;
  int tid = threadIdx.x;
  const float2* p2 = reinterpret_cast<const float2*>(probs);
  __shared__ int h[257];
  for (int i = tid; i < 257; i += 256) h[i] = 0;
  if (bx == 0) {
    if (tid < 257) bfill[b * 257 + tid] = 0;
    if (tid < NT) scnt[b * NT + tid] = 0;
    if (tid < 65) cellCnt[b * 65 + tid] = 0;
  }
  __syncthreads();
  int stride = gridDim.x * blockDim.x;
  for (int a = bx * blockDim.x + tid; a < NA; a += stride) {
    float sc = p2[(size_t)b * NA + a].y;
    int bk = bucket_of(__float_as_uint(sc));
    atomicAdd(&h[bk < 0 ? 256 : bk], 1);
  }
  __syncthreads();
  if (tid < 256) histPB[((size_t)b * 64 + bx) * 256 + tid] = h[tid];
}

// K2: inline select + scatter candidate keys into bucket segments
__global__ __launch_bounds__(256) void gather_kernel(const float* __restrict__ probs,
                                                     const int* __restrict__ histPB,
                                                     int* __restrict__ bfill,
                                                     u64* __restrict__ cand) {
  int b = blockIdx.y;
  const float2* p2 = reinterpret_cast<const float2*>(probs);
  __shared__ int h[256];
  __shared__ int bst[256];
  __shared__ int tb_s;
  prefix_from_hist(histPB, b, h, bst, &tb_s);
  int tb = tb_s;
  int stride = gridDim.x * blockDim.x;
  for (int a = blockIdx.x * blockDim.x + threadIdx.x; a < NA; a += stride) {
    float sc = p2[(size_t)b * NA + a].y;
    u32 bits = __float_as_uint(sc);
    int bk = bucket_of(bits);
    if (bk >= tb) {
      int pos = bst[bk] + atomicAdd(&bfill[b * 257 + bk], 1);
      if (pos < CAND_CAP)
        cand[(size_t)b * CAND_CAP + pos] = ((u64)bits << 32) | (u64)(0xFFFFFFFFu - (u32)a);
    }
  }
}

// K3: per-(batch,bucket-slot) bitonic sort of <=1024 keys in LDS,
// then decode+clip+bin its own ranks directly from LDS.
// Also zeroes tileT for this batch (runs before pairs_kernel).
__global__ __launch_bounds__(256) void sortdecode_kernel(const int* __restrict__ histPB,
                                                         const int* __restrict__ bfill,
                                                         const u64* __restrict__ cand,
                                                         const float* __restrict__ anchors,
                                                         const float* __restrict__ deltas,
                                                         float4* __restrict__ boxes,
                                                         int* __restrict__ cellCnt,
                                                         u16* __restrict__ cellList,
                                                         u16* __restrict__ largeList,
                                                         u64* __restrict__ tileT) {
  int b = blockIdx.y;
  int tid = threadIdx.x;
  for (int g = blockIdx.x * 256 + tid; g < NT * TILE * 4; g += 64 * 256)
    tileT[(size_t)b * (NT * TILE * 4) + g] = 0ULL;
  __shared__ int h[256];
  __shared__ int bst[256];
  __shared__ int tb_s;
  prefix_from_hist(histPB, b, h, bst, &tb_s);
  if (blockIdx.x == 0) {
    float4 z = {0.f, 0.f, 0.f, 0.f};
    for (int r = NSEL + tid; r < NPAD; r += 256) boxes[(size_t)b * NPAD + r] = z;
  }
  int v = tb_s + blockIdx.x;
  if (v > 255) return;
  int start = bst[v];
  if (start >= NSEL) return;  // ranks beyond NSEL are never consumed
  int cnt = min(min(bfill[b * 257 + v], 1024), CAND_CAP - start);
  if (cnt <= 0) return;
  const u64* seg = cand + (size_t)b * CAND_CAP + start;
  __shared__ u64 s[1024];
  u64 x[4];
#pragma unroll
  for (int p = 0; p < 4; ++p) {
    int i = p * 256 + tid;
    x[p] = (i < cnt) ? seg[i] : 0ULL;
  }
  for (int k = 2; k <= 64; k <<= 1) {
    for (int j = k >> 1; j >= 1; j >>= 1) {
#pragma unroll
      for (int p = 0; p < 4; ++p) {
        int i = p * 256 + tid;
        u64 pv = shfl_xor_u64(x[p], j);
        bool takemax = (((i & j) == 0) == ((i & k) == 0));
        u64 mx = x[p] > pv ? x[p] : pv;
        u64 mn = x[p] < pv ? x[p] : pv;
        x[p] = takemax ? mx : mn;
      }
    }
  }
#pragma unroll
  for (int p = 0; p < 4; ++p) s[p * 256 + tid] = x[p];
  __syncthreads();
  for (int k = 128; k <= 1024; k <<= 1) {
    for (int j = k >> 1; j >= 64; j >>= 1) {
      for (int q = tid; q < 512; q += 256) {
        int i = ((q & ~(j - 1)) << 1) | (q & (j - 1));
        int ixj = i | j;
        u64 a = s[i], c = s[ixj];
        bool up = ((i & k) == 0);
        if (up ? (a < c) : (a > c)) { s[i] = c; s[ixj] = a; }
      }
      __syncthreads();
    }
#pragma unroll
    for (int p = 0; p < 4; ++p) x[p] = s[p * 256 + tid];
    for (int j = 32; j >= 1; j >>= 1) {
#pragma unroll
      for (int p = 0; p < 4; ++p) {
        int i = p * 256 + tid;
        u64 pv = shfl_xor_u64(x[p], j);
        bool takemax = (((i & j) == 0) == ((i & k) == 0));
        u64 mx = x[p] > pv ? x[p] : pv;
        u64 mn = x[p] < pv ? x[p] : pv;
        x[p] = takemax ? mx : mn;
      }
    }
    __syncthreads();
#pragma unroll
    for (int p = 0; p < 4; ++p) s[p * 256 + tid] = x[p];
    __syncthreads();
  }
  // decode + clip + bin ranks [start, start+cnt) ∩ [0, NSEL)
  for (int i = tid; i < cnt; i += 256) {
    int r = start + i;
    if (r >= NSEL) continue;
    u64 key = s[i];
    float4 o = {0.f, 0.f, 0.f, 0.f};
    u32 idx = 0xFFFFFFFFu - (u32)(key & 0xFFFFFFFFu);
    if (idx < NA) {
      float4 av = *reinterpret_cast<const float4*>(anchors + ((size_t)b * NA + idx) * 4);
      float4 dv = *reinterpret_cast<const float4*>(deltas + ((size_t)b * NA + idx) * 4);
      float y1 = av.x, x1 = av.y, y2 = av.z, x2 = av.w;
      float dy = dv.x * 0.1f, dx = dv.y * 0.1f;
      float dh = dv.z * 0.2f, dw = dv.w * 0.2f;
      float hh = y2 - y1, ww = x2 - x1;
      float cy = y1 + 0.5f * hh + dy * hh;
      float cx = x1 + 0.5f * ww + dx * ww;
      hh = hh * expf(dh);
      ww = ww * expf(dw);
      float ny1 = cy - 0.5f * hh, nx1 = cx - 0.5f * ww;
      float ny2 = ny1 + hh, nx2 = nx1 + ww;
      o.x = fminf(fmaxf(ny1, 0.f), 1.f);
      o.y = fminf(fmaxf(nx1, 0.f), 1.f);
      o.z = fminf(fmaxf(ny2, 0.f), 1.f);
      o.w = fminf(fmaxf(nx2, 0.f), 1.f);
    }
    boxes[(size_t)b * NPAD + r] = o;
    float bh = o.z - o.x, bw = o.w - o.y;
    if (bh > LTHR || bw > LTHR) {
      int pos = atomicAdd(&cellCnt[b * 65 + 64], 1);
      if (pos < LARGECAP) largeList[b * LARGECAP + pos] = (u16)r;
    } else {
      int gy = min(7, max(0, (int)((o.x + o.z) * 4.0f)));
      int gx = min(7, max(0, (int)((o.y + o.w) * 4.0f)));
      int cell = gy * 8 + gx;
      int pos = atomicAdd(&cellCnt[b * 65 + cell], 1);
      if (pos < CELLCAP) cellList[((size_t)b * 64 + cell) * CELLCAP + pos] = (u16)r;
    }
  }
}

// K4: blocks 0..63 = per-cell {self + boundary-band-filtered cross};
// blocks 64..127 = large-box window tests + large-large pairs.
__global__ __launch_bounds__(256) void pairs_kernel(const float4* __restrict__ boxes,
                                                    const u16* __restrict__ cellList,
                                                    const u16* __restrict__ largeList,
                                                    const int* __restrict__ cellCnt,
                                                    u64* __restrict__ tileT,
                                                    u32* __restrict__ sent,
                                                    int* __restrict__ scnt) {
  int b = blockIdx.y;
  int tid = threadIdx.x;
  if (blockIdx.x >= 64) {
    // ---- large path ----
    int lb = blockIdx.x - 64;  // 0..63
    int nL = min(cellCnt[b * 65 + 64], LARGECAP);
    if (nL == 0) return;
    for (int li = lb; li < nL; li += 64) {
      int L = largeList[b * LARGECAP + li];
      float4 Lb = boxes[(size_t)b * NPAD + L];
      float hL = Lb.z - Lb.x, wL = Lb.w - Lb.y;
      if (0.7f * hL >= 0.126f || 0.7f * wL >= 0.126f) continue;  // no small can match
      float La = hL * wL;
      float sLy = Lb.x + Lb.z, sLx = Lb.y + Lb.w;
      int gy0 = max(0, (int)((sLy - 0.08f) * 4.0f));
      int gy1 = min(7, (int)((sLy + 0.08f) * 4.0f));
      int gx0 = max(0, (int)((sLx - 0.08f) * 4.0f));
      int gx1 = min(7, (int)((sLx + 0.08f) * 4.0f));
      for (int gy = gy0; gy <= gy1; ++gy)
        for (int gx = gx0; gx <= gx1; ++gx) {
          int cc = gy * 8 + gx;
          int cnt = min(cellCnt[b * 65 + cc], CELLCAP);
          for (int i = tid; i < cnt; i += 256) {
            int r = cellList[((size_t)b * 64 + cc) * CELLCAP + i];
            float4 jb = boxes[(size_t)b * NPAD + r];
            float ja = (jb.z - jb.x) * (jb.w - jb.y);
            if (iou_gt(Lb, jb, La, ja)) emit_pair(b, L, r, tileT, sent, scnt);
          }
        }
    }
    // large-large, list-index i<j
    int s = 1;
    while ((1 << s) < nL) ++s;
    int tot = nL << s, m = (1 << s) - 1;
    int stride = 64 * 256;
    for (int t = lb * 256 + tid; t < tot; t += stride) {
      int i = t >> s, j = t & m;
      if (j >= nL || i >= j) continue;
      int Li = largeList[b * LARGECAP + i];
      int Lj = largeList[b * LARGECAP + j];
      float4 A = boxes[(size_t)b * NPAD + Li];
      float4 B = boxes[(size_t)b * NPAD + Lj];
      float aA = (A.z - A.x) * (A.w - A.y);
      float aB = (B.z - B.x) * (B.w - B.y);
      if (iou_gt(A, B, aA, aB)) emit_pair(b, Li, Lj, tileT, sent, scnt);
    }
    return;
  }
  // ---- cell path ----
  int c = blockIdx.x;
  int cy = c >> 3, cx = c & 7;
  int nA = min(cellCnt[b * 65 + c], CELLCAP);
  if (nA == 0) return;
  __shared__ float4 Ab[CELLCAP];
  __shared__ float Aa[CELLCAP];
  __shared__ float Asx[CELLCAP];  // x1+x2 = 2*center_x
  __shared__ float Asy[CELLCAP];  // y1+y2 = 2*center_y
  __shared__ u16 Ai[CELLCAP];
  __shared__ u16 fAi[CELLCAP];
  __shared__ float4 Bb[3 * CELLCAP];
  __shared__ float Ba[3 * CELLCAP];
  __shared__ u16 Bi[3 * CELLCAP];
  __shared__ int nfA_s, nfB_s;
  for (int i = tid; i < nA; i += 256) {
    int r = cellList[((size_t)b * 64 + c) * CELLCAP + i];
    float4 bx = boxes[(size_t)b * NPAD + r];
    Ab[i] = bx;
    Aa[i] = (bx.z - bx.x) * (bx.w - bx.y);
    Asy[i] = bx.x + bx.z;
    Asx[i] = bx.y + bx.w;
    Ai[i] = (u16)r;
  }
  __syncthreads();
  // self pairs: exact triangular enumeration
  {
    int totS = (nA * (nA - 1)) >> 1;
    for (int t = tid; t < totS; t += 256) {
      int i = (int)((1.0f + sqrtf(8.0f * (float)t + 1.0f)) * 0.5f);
      int tri = (i * (i - 1)) >> 1;
      if (t < tri) {
        --i;
        tri = (i * (i - 1)) >> 1;
      } else if (t >= tri + i) {
        tri += i;
        ++i;
      }
      int j = t - tri;
      if (iou_gt(Ab[i], Ab[j], Aa[i], Aa[j]))
        emit_pair(b, Ai[i], Ai[j], tileT, sent, scnt);
    }
  }
  // phase R: right neighbor, x boundary band
  if (cx < 7) {
    __syncthreads();
    if (tid == 0) { nfA_s = 0; nfB_s = 0; }
    __syncthreads();
    float XR2 = (float)(cx + 1) * 0.25f;
    for (int i = tid; i < nA; i += 256)
      if (Asx[i] > XR2 - 0.078f) fAi[atomicAdd(&nfA_s, 1)] = (u16)i;
    int nc = c + 1;
    int nN = min(cellCnt[b * 65 + nc], CELLCAP);
    for (int i = tid; i < nN; i += 256) {
      int r = cellList[((size_t)b * 64 + nc) * CELLCAP + i];
      float4 bx = boxes[(size_t)b * NPAD + r];
      if (bx.y + bx.w < XR2 + 0.078f) {
        int p = atomicAdd(&nfB_s, 1);
        Bb[p] = bx;
        Ba[p] = (bx.z - bx.x) * (bx.w - bx.y);
        Bi[p] = (u16)r;
      }
    }
    __syncthreads();
    int nfA = nfA_s, nfB = nfB_s;
    if (nfA && nfB) {
      int s = 1;
      while ((1 << s) < nfB) ++s;
      int tot = nfA << s, m = (1 << s) - 1;
      for (int t = tid; t < tot; t += 256) {
        int ii = fAi[t >> s], j = t & m;
        if (j < nfB && iou_gt(Ab[ii], Bb[j], Aa[ii], Ba[j]))
          emit_pair(b, Ai[ii], Bi[j], tileT, sent, scnt);
      }
    }
  }
  // phase D: three lower neighbors, y band (+x band for diagonals at staging)
  if (cy < 7) {
    __syncthreads();
    if (tid == 0) { nfA_s = 0; nfB_s = 0; }
    __syncthreads();
    float YB2 = (float)(cy + 1) * 0.25f;
    float XL2 = (float)cx * 0.25f;
    float XR2 = (float)(cx + 1) * 0.25f;
    for (int i = tid; i < nA; i += 256)
      if (Asy[i] > YB2 - 0.078f) fAi[atomicAdd(&nfA_s, 1)] = (u16)i;
    for (int k = 0; k < 3; ++k) {
      int nx = cx + k - 1;
      if (nx < 0 || nx > 7) continue;
      int nc = (cy + 1) * 8 + nx;
      int nN = min(cellCnt[b * 65 + nc], CELLCAP);
      for (int i = tid; i < nN; i += 256) {
        int r = cellList[((size_t)b * 64 + nc) * CELLCAP + i];
        float4 bx = boxes[(size_t)b * NPAD + r];
        float bsy = bx.x + bx.z, bsx = bx.y + bx.w;
        bool ok = bsy < YB2 + 0.078f;
        if (k == 0) ok = ok && (bsx > XL2 - 0.078f);
        if (k == 2) ok = ok && (bsx < XR2 + 0.078f);
        if (ok) {
          int p = atomicAdd(&nfB_s, 1);
          Bb[p] = bx;
          Ba[p] = (bx.z - bx.x) * (bx.w - bx.y);
          Bi[p] = (u16)r;
        }
      }
    }
    __syncthreads();
    int nfA = nfA_s, nfB = nfB_s;
    if (nfA && nfB) {
      int s = 1;
      while ((1 << s) < nfB) ++s;
      int tot = nfA << s, m = (1 << s) - 1;
      for (int t = tid; t < tot; t += 256) {
        int ii = fAi[t >> s], j = t & m;
        if (j < nfB && iou_gt(Ab[ii], Bb[j], Aa[ii], Ba[j]))
          emit_pair(b, Ai[ii], Bi[j], tileT, sent, scnt);
      }
    }
  }
}

// K5: greedy NMS, 256-box TILE scan (round-4 verified version).
__global__ __launch_bounds__(512) void nms_kernel(const u32* __restrict__ sent,
                                                  const int* __restrict__ scnt,
                                                  const u64* __restrict__ tileT,
                                                  const float4* __restrict__ boxes,
                                                  float4* __restrict__ out) {
  int b = blockIdx.x;
  int tid = threadIdx.x;
  int lane = tid & 63;
  int wv = tid >> 6;
  __shared__ u32 entS[LDSE];        // 49152 B
  __shared__ u32 rmb[TILE];         // 1024 B
  __shared__ u64 Kall[NWORD];       // 768 B
  __shared__ int cw[NT];
  __shared__ int prefix[NT + 1];
  __shared__ int baseT[NT];
  if (tid < NT) cw[tid] = min(scnt[b * NT + tid], SCAP);
  if (tid < TILE) rmb[tid] = 0u;
  if (tid < NWORD) Kall[tid] = 0ULL;
  {
    float4 z = {0.f, 0.f, 0.f, 0.f};
    for (int i = tid; i < PROP; i += 512) out[(size_t)b * PROP + i] = z;
  }
  __syncthreads();
  if (tid == 0) {
    int run = 0;
    for (int t = 0; t < NT; ++t) { prefix[t] = run; run += cw[t]; }
    prefix[NT] = run;
  }
  __syncthreads();
  for (int t = wv; t < NT; t += 8) {
    const u32* gb = sent + (size_t)(b * NT + t) * SCAP;
    int base = prefix[t], n = cw[t];
    for (int e = lane; e < n; e += 64) {
      int slot = base + e;
      if (slot < LDSE) entS[slot] = gb[e];
    }
  }
  __syncthreads();
  if (wv == 0) {
    const u64* tb0 = tileT + (size_t)b * (NT * TILE * 4);
    u64 mc[4][4], mn[4][4];
#pragma unroll
    for (int q = 0; q < 4; ++q)
#pragma unroll
      for (int j = 0; j < 4; ++j)
        mc[q][j] = tb0[(size_t)(q * 64 + lane) * 4 + j];
    int total = 0;
    for (int t = 0; t < NT; ++t) {
      if (t + 1 < NT) {
        const u64* nb = tb0 + (size_t)(t + 1) * (TILE * 4);
#pragma unroll
        for (int q = 0; q < 4; ++q)
#pragma unroll
          for (int j = 0; j < 4; ++j)
            mn[q][j] = nb[(size_t)(q * 64 + lane) * 4 + j];
      }
      {
        int n = cw[t], base = prefix[t];
        for (int e = lane; e < n; e += 64) {
          int slot = base + e;
          u32 ent = (slot < LDSE) ? entS[slot] : sent[(size_t)(b * NT + t) * SCAP + e];
          int srcr = (int)(ent >> 8);
          if ((Kall[srcr >> 6] >> (srcr & 63)) & 1ULL) rmb[ent & 255] = 1u;
        }
      }
      u32 f0 = rmb[lane], f1 = rmb[64 + lane], f2 = rmb[128 + lane], f3 = rmb[192 + lane];
      rmb[lane] = 0u;
      rmb[64 + lane] = 0u;
      rmb[128 + lane] = 0u;
      rmb[192 + lane] = 0u;
      int gw = t * 4;
      u64 K0, K1, K2, K3;
      {
        bool alive0 = (f0 == 0u) && ((valid_mask(gw) >> lane) & 1ULL);
        u64 cm = mc[0][0];
        u64 K = __ballot(alive0);
        for (int it = 0; it < 70; ++it) {
          bool alive = alive0 && ((K & cm) == 0ULL);
          u64 Kn = __ballot(alive);
          if (Kn == K) break;
          K = Kn;
        }
        K0 = K;
      }
      {
        u64 pre = K0 & mc[1][0];
        bool alive0 = (f1 == 0u) && ((valid_mask(gw + 1) >> lane) & 1ULL) && (pre == 0ULL);
        u64 cm = mc[1][1];
        u64 K = __ballot(alive0);
        for (int it = 0; it < 70; ++it) {
          bool alive = alive0 && ((K & cm) == 0ULL);
          u64 Kn = __ballot(alive);
          if (Kn == K) break;
          K = Kn;
        }
        K1 = K;
      }
      {
        u64 pre = (K0 & mc[2][0]) | (K1 & mc[2][1]);
        bool alive0 = (f2 == 0u) && ((valid_mask(gw + 2) >> lane) & 1ULL) && (pre == 0ULL);
        u64 cm = mc[2][2];
        u64 K = __ballot(alive0);
        for (int it = 0; it < 70; ++it) {
          bool alive = alive0 && ((K & cm) == 0ULL);
          u64 Kn = __ballot(alive);
          if (Kn == K) break;
          K = Kn;
        }
        K2 = K;
      }
      {
        u64 pre = (K0 & mc[3][0]) | (K1 & mc[3][1]) | (K2 & mc[3][2]);
        bool alive0 = (f3 == 0u) && ((valid_mask(gw + 3) >> lane) & 1ULL) && (pre == 0ULL);
        u64 cm = mc[3][3];
        u64 K = __ballot(alive0);
        for (int it = 0; it < 70; ++it) {
          bool alive = alive0 && ((K & cm) == 0ULL);
          u64 Kn = __ballot(alive);
          if (Kn == K) break;
          K = Kn;
        }
        K3 = K;
      }
      if (lane == 0) {
        Kall[gw] = K0;
        Kall[gw + 1] = K1;
        Kall[gw + 2] = K2;
        Kall[gw + 3] = K3;
        baseT[t] = total;
      }
      total += __popcll(K0) + __popcll(K1) + __popcll(K2) + __popcll(K3);
#pragma unroll
      for (int q = 0; q < 4; ++q)
#pragma unroll
        for (int j = 0; j < 4; ++j)
          mc[q][j] = mn[q][j];
    }
  }
  __syncthreads();
  for (int i = tid; i < NSEL; i += 512) {
    int g = i >> 6, bb = i & 63;
    u64 K = Kall[g];
    if ((K >> bb) & 1ULL) {
      int t = i >> 8;
      int rank = baseT[t];
      for (int q = t * 4; q < g; ++q) rank += __popcll(Kall[q]);
      rank += __popcll(K & ((1ULL << bb) - 1ULL));
      if (rank < PROP) out[(size_t)b * PROP + rank] = boxes[(size_t)b * NPAD + i];
    }
  }
}

extern "C" void kernel_launch(void* const* d_in, const int* in_sizes, int n_in,
                              void* d_out, int out_size, void* d_ws, size_t ws_size,
                              hipStream_t stream) {
  const float* probs = (const float*)d_in[0];    // (8,131072,2)
  const float* deltas = (const float*)d_in[1];   // (8,131072,4)
  const float* anchors = (const float*)d_in[2];  // (8,131072,4)
  char* ws = (char*)d_ws;
  int* histPB = (int*)(ws + OFF_HISTPB);
  int* bfill = (int*)(ws + OFF_BFILL);
  int* scnt = (int*)(ws + OFF_SCNT);
  int* cellCnt = (int*)(ws + OFF_CELLCNT);
  u64* tileT = (u64*)(ws + OFF_TILET);
  u64* cand = (u64*)(ws + OFF_CAND);
  float4* boxes = (float4*)(ws + OFF_BOXES);
  u16* cellList = (u16*)(ws + OFF_CELLLIST);
  u16* largeList = (u16*)(ws + OFF_LARGE);
  u32* sent = (u32*)(ws + OFF_SENT);

  hist_kernel<<<dim3(64, BATCH), 256, 0, stream>>>(probs, histPB, bfill, scnt, cellCnt);
  gather_kernel<<<dim3(64, BATCH), 256, 0, stream>>>(probs, histPB, bfill, cand);
  sortdecode_kernel<<<dim3(64, BATCH), 256, 0, stream>>>(histPB, bfill, cand, anchors,
                                                         deltas, boxes, cellCnt,
                                                         cellList, largeList, tileT);
  pairs_kernel<<<dim3(128, BATCH), 256, 0, stream>>>(boxes, cellList, largeList,
                                                     cellCnt, tileT, sent, scnt);
  nms_kernel<<<BATCH, 512, 0, stream>>>(sent, scnt, tileT, boxes, (float4*)d_out);
}

// Round 8
// 203.376 us; speedup vs baseline: 1.8616x; 1.0781x over previous
//
#include <hip/hip_runtime.h>

#pragma clang fp contract(off)

typedef unsigned long long u64;
typedef unsigned int u32;
typedef unsigned short u16;

#define BATCH 8
#define NA 131072
#define NSEL 6000
#define NT 24                 // 256-box tiles
#define TILE 256
#define NWORD (NT * 4)        // 96 64-bit words
#define NPAD (NT * TILE)      // 6144
#define CAND_CAP 8192
#define PROP 1000
#define SCAP 4096             // cross-tile entries cap per (batch, DEST tile)
#define LDSE 12288            // entries staged in LDS (u32 each)
#define CELLCAP 256           // boxes per 8x8 grid cell (mean ~94)
#define LARGECAP 1024         // "large" boxes per batch (dim > 1/8)
#define LTHR 0.125f
#define HB 16                 // hist blocks per batch (rows to sum)

// ---- workspace layout (bytes); NOTHING is pre-zeroed by the host ----
// histPB rows fully overwritten each launch; bfill/scnt/cellCnt zeroed by
// hist_kernel block 0 of each batch (ordered by launch boundary); tileT
// zeroed inside sortdecode_kernel; cand/sent/boxes bounds-guarded.
#define OFF_HISTPB   0            // BATCH*HB*256*4 = 131072
#define OFF_BFILL    131072       // 8224 -> 139296 (pad 139328)
#define OFF_SCNT     139328       // 768 -> 140096 (pad 140160)
#define OFF_CELLCNT  140160       // 2080 -> 142240 (pad 142272)
#define OFF_TILET    142272       // 1572864 -> 1715136
#define OFF_CAND     1715136      // 524288 -> 2239424
#define OFF_BOXES    2239424      // 786432 -> 3025856
#define OFF_CELLLIST 3025856      // 262144 -> 3288000
#define OFF_LARGE    3288000      // 16384 -> 3304384
#define OFF_SENT     3304384      // 3145728 -> 6450112

__device__ __forceinline__ int bucket_of(u32 bits) {
  u32 hi = bits >> 16;
  if (hi >= 0x3E80u && hi < 0x3F80u) return (int)(hi - 0x3E80u);
  if (hi >= 0x3F80u && hi < 0x8000u) return 255;
  return -1;
}

// "RN32(inter / max(uni,1e-12)) > 0.7f" without fp32 divide, bit-exact:
// M=0x1.666667p-1 is the 0.7f/nextafter midpoint; RN32(t)>0.7f <=> t>=M;
// a/b>=M <=> a>=M*b, exact in fp64 (25-bit x 24-bit product).
__device__ __forceinline__ bool iou_gt(float4 A, float4 B, float areaA, float areaB) {
  float iy = fminf(A.z, B.z) - fmaxf(A.x, B.x);
  float ix = fminf(A.w, B.w) - fmaxf(A.y, B.y);
  float inter = fmaxf(iy, 0.0f) * fmaxf(ix, 0.0f);
  float uni = (areaA + areaB) - inter;
  float uc = fmaxf(uni, 1e-12f);
  return (double)inter >= 0x1.666667p-1 * (double)uc;
}

// Within-tile pairs -> dense bit matrix tileT[b][t][dst&255][(src&255)>>6].
// Cross-tile pairs -> u32 entry (src<<8)|(dst&255) in segment (b, dst_tile).
__device__ __forceinline__ void emit_pair(int b, int ra, int rb, u64* tileT,
                                          u32* sent, int* scnt) {
  int src = min(ra, rb), dst = max(ra, rb);
  int tsrc = src >> 8, tdst = dst >> 8;
  if (tsrc == tdst) {
    atomicOr(&tileT[(((size_t)b * NT + tdst) * TILE + (dst & 255)) * 4 + ((src >> 6) & 3)],
             1ULL << (src & 63));
  } else {
    int e = atomicAdd(&scnt[b * NT + tdst], 1);
    if (e < SCAP)
      sent[(size_t)(b * NT + tdst) * SCAP + e] = ((u32)src << 8) | (u32)(dst & 255);
  }
}

__device__ __forceinline__ u64 shfl_xor_u64(u64 v, int lanemask) {
  u32 lo = (u32)v, hi = (u32)(v >> 32);
  lo = (u32)__shfl_xor((int)lo, lanemask);
  hi = (u32)__shfl_xor((int)hi, lanemask);
  return ((u64)hi << 32) | (u64)lo;
}

__device__ __forceinline__ u64 valid_mask(int g) {
  int lo = g * 64;
  if (lo + 64 <= NSEL) return ~0ULL;
  if (lo >= NSEL) return 0ULL;
  return (1ULL << (NSEL - lo)) - 1ULL;
}

// PARALLEL descending-suffix scan of the 16-row per-block histogram.
// h[v] = sum of rows; suf[v] = sum_{u>=v} h[u] (Hillis-Steele, 8 rounds);
// bst[v] = suf[v]-h[v] = sum_{u>v}; tb = largest v with suf[v] >= NSEL.
// Identical integer arithmetic to the serial loop (verified rounds 5/6)
// -> bit-identical tb/bst in every block.
__device__ __forceinline__ void prefix_from_hist(const int* __restrict__ histPB,
                                                 int b, int* h, int* suf,
                                                 int* bst, int* tb_s) {
  int tid = threadIdx.x;
  {
    const int* hp = histPB + (size_t)b * (HB * 256) + tid;
    int acc = 0;
#pragma unroll
    for (int k = 0; k < HB; ++k) acc += hp[k * 256];
    h[tid] = acc;
    suf[tid] = acc;
  }
  if (tid == 0) *tb_s = 0;
  __syncthreads();
  for (int d = 1; d < 256; d <<= 1) {
    int add = (tid + d < 256) ? suf[tid + d] : 0;
    __syncthreads();
    suf[tid] += add;
    __syncthreads();
  }
  bst[tid] = suf[tid] - h[tid];
  if (suf[tid] >= NSEL && (tid == 255 || suf[tid + 1] < NSEL)) *tb_s = tid;
  __syncthreads();
}

// Bitonic sort (descending) of NS = P*256 keys, 256 threads, P regs/thread.
// P=2 path (cnt<=512) produces s[0..512) identical to the P=4 path: the
// all-zero upper half of the 1024-wide sort never perturbs the lower 512
// (final merge compares real keys against zeros and never swaps).
template <int P>
__device__ __forceinline__ void bitonic_sort(u64* s, const u64* __restrict__ seg,
                                             int cnt, int tid) {
  const int NS = P * 256;
  u64 x[P];
#pragma unroll
  for (int p = 0; p < P; ++p) {
    int i = p * 256 + tid;
    x[p] = (i < cnt) ? seg[i] : 0ULL;
  }
  for (int k = 2; k <= 64; k <<= 1) {
    for (int j = k >> 1; j >= 1; j >>= 1) {
#pragma unroll
      for (int p = 0; p < P; ++p) {
        int i = p * 256 + tid;
        u64 pv = shfl_xor_u64(x[p], j);
        bool takemax = (((i & j) == 0) == ((i & k) == 0));
        u64 mx = x[p] > pv ? x[p] : pv;
        u64 mn = x[p] < pv ? x[p] : pv;
        x[p] = takemax ? mx : mn;
      }
    }
  }
#pragma unroll
  for (int p = 0; p < P; ++p) s[p * 256 + tid] = x[p];
  __syncthreads();
  for (int k = 128; k <= NS; k <<= 1) {
    for (int j = k >> 1; j >= 64; j >>= 1) {
      for (int q = tid; q < NS / 2; q += 256) {
        int i = ((q & ~(j - 1)) << 1) | (q & (j - 1));
        int ixj = i | j;
        u64 a = s[i], c = s[ixj];
        bool up = ((i & k) == 0);
        if (up ? (a < c) : (a > c)) { s[i] = c; s[ixj] = a; }
      }
      __syncthreads();
    }
#pragma unroll
    for (int p = 0; p < P; ++p) x[p] = s[p * 256 + tid];
    for (int j = 32; j >= 1; j >>= 1) {
#pragma unroll
      for (int p = 0; p < P; ++p) {
        int i = p * 256 + tid;
        u64 pv = shfl_xor_u64(x[p], j);
        bool takemax = (((i & j) == 0) == ((i & k) == 0));
        u64 mx = x[p] > pv ? x[p] : pv;
        u64 mn = x[p] < pv ? x[p] : pv;
        x[p] = takemax ? mx : mn;
      }
    }
    __syncthreads();
#pragma unroll
    for (int p = 0; p < P; ++p) s[p * 256 + tid] = x[p];
    __syncthreads();
  }
}

// K1: per-batch per-BLOCK 256-bucket histogram (non-atomic global write),
// HB=16 blocks per batch. Block 0 also zeroes bfill/scnt/cellCnt.
__global__ __launch_bounds__(256) void hist_kernel(const float* __restrict__ probs,
                                                   int* __restrict__ histPB,
                                                   int* __restrict__ bfill,
                                                   int* __restrict__ scnt,
                                                   int* __restrict__ cellCnt) {
  int b = blockIdx.y;
  int bx = blockIdx.x;
  int tid = threadIdx.x;
  const float2* p2 = reinterpret_cast<const float2*>(probs);
  __shared__ int h[257];
  for (int i = tid; i < 257; i += 256) h[i] = 0;
  if (bx == 0) {
    if (tid < 257) bfill[b * 257 + tid] = 0;
    if (tid < NT) scnt[b * NT + tid] = 0;
    if (tid < 65) cellCnt[b * 65 + tid] = 0;
  }
  __syncthreads();
  int stride = gridDim.x * blockDim.x;
  for (int a = bx * blockDim.x + tid; a < NA; a += stride) {
    float sc = p2[(size_t)b * NA + a].y;
    int bk = bucket_of(__float_as_uint(sc));
    atomicAdd(&h[bk < 0 ? 256 : bk], 1);
  }
  __syncthreads();
  if (tid < 256) histPB[((size_t)b * HB + bx) * 256 + tid] = h[tid];
}

// K2: inline select + scatter candidate keys into bucket segments
__global__ __launch_bounds__(256) void gather_kernel(const float* __restrict__ probs,
                                                     const int* __restrict__ histPB,
                                                     int* __restrict__ bfill,
                                                     u64* __restrict__ cand) {
  int b = blockIdx.y;
  const float2* p2 = reinterpret_cast<const float2*>(probs);
  __shared__ int h[256];
  __shared__ int suf[256];
  __shared__ int bst[256];
  __shared__ int tb_s;
  prefix_from_hist(histPB, b, h, suf, bst, &tb_s);
  int tb = tb_s;
  int stride = gridDim.x * blockDim.x;
  for (int a = blockIdx.x * blockDim.x + threadIdx.x; a < NA; a += stride) {
    float sc = p2[(size_t)b * NA + a].y;
    u32 bits = __float_as_uint(sc);
    int bk = bucket_of(bits);
    if (bk >= tb) {
      int pos = bst[bk] + atomicAdd(&bfill[b * 257 + bk], 1);
      if (pos < CAND_CAP)
        cand[(size_t)b * CAND_CAP + pos] = ((u64)bits << 32) | (u64)(0xFFFFFFFFu - (u32)a);
    }
  }
}

// K3: per-(batch,bucket-slot) bitonic sort (adaptive 512/1024 wide) in LDS,
// then decode+clip+bin its own ranks directly from LDS.
// Also zeroes tileT for this batch (runs before pairs_kernel).
__global__ __launch_bounds__(256) void sortdecode_kernel(const int* __restrict__ histPB,
                                                         const int* __restrict__ bfill,
                                                         const u64* __restrict__ cand,
                                                         const float* __restrict__ anchors,
                                                         const float* __restrict__ deltas,
                                                         float4* __restrict__ boxes,
                                                         int* __restrict__ cellCnt,
                                                         u16* __restrict__ cellList,
                                                         u16* __restrict__ largeList,
                                                         u64* __restrict__ tileT) {
  int b = blockIdx.y;
  int tid = threadIdx.x;
  for (int g = blockIdx.x * 256 + tid; g < NT * TILE * 4; g += 64 * 256)
    tileT[(size_t)b * (NT * TILE * 4) + g] = 0ULL;
  __shared__ int h[256];
  __shared__ int suf[256];
  __shared__ int bst[256];
  __shared__ int tb_s;
  prefix_from_hist(histPB, b, h, suf, bst, &tb_s);
  if (blockIdx.x == 0) {
    float4 z = {0.f, 0.f, 0.f, 0.f};
    for (int r = NSEL + tid; r < NPAD; r += 256) boxes[(size_t)b * NPAD + r] = z;
  }
  int v = tb_s + blockIdx.x;
  if (v > 255) return;
  int start = bst[v];
  if (start >= NSEL) return;  // ranks beyond NSEL are never consumed
  int cnt = min(min(bfill[b * 257 + v], 1024), CAND_CAP - start);
  if (cnt <= 0) return;
  const u64* seg = cand + (size_t)b * CAND_CAP + start;
  __shared__ u64 s[1024];
  if (cnt <= 512)
    bitonic_sort<2>(s, seg, cnt, tid);
  else
    bitonic_sort<4>(s, seg, cnt, tid);
  // decode + clip + bin ranks [start, start+cnt) ∩ [0, NSEL)
  for (int i = tid; i < cnt; i += 256) {
    int r = start + i;
    if (r >= NSEL) continue;
    u64 key = s[i];
    float4 o = {0.f, 0.f, 0.f, 0.f};
    u32 idx = 0xFFFFFFFFu - (u32)(key & 0xFFFFFFFFu);
    if (idx < NA) {
      float4 av = *reinterpret_cast<const float4*>(anchors + ((size_t)b * NA + idx) * 4);
      float4 dv = *reinterpret_cast<const float4*>(deltas + ((size_t)b * NA + idx) * 4);
      float y1 = av.x, x1 = av.y, y2 = av.z, x2 = av.w;
      float dy = dv.x * 0.1f, dx = dv.y * 0.1f;
      float dh = dv.z * 0.2f, dw = dv.w * 0.2f;
      float hh = y2 - y1, ww = x2 - x1;
      float cy = y1 + 0.5f * hh + dy * hh;
      float cx = x1 + 0.5f * ww + dx * ww;
      hh = hh * expf(dh);
      ww = ww * expf(dw);
      float ny1 = cy - 0.5f * hh, nx1 = cx - 0.5f * ww;
      float ny2 = ny1 + hh, nx2 = nx1 + ww;
      o.x = fminf(fmaxf(ny1, 0.f), 1.f);
      o.y = fminf(fmaxf(nx1, 0.f), 1.f);
      o.z = fminf(fmaxf(ny2, 0.f), 1.f);
      o.w = fminf(fmaxf(nx2, 0.f), 1.f);
    }
    boxes[(size_t)b * NPAD + r] = o;
    float bh = o.z - o.x, bw = o.w - o.y;
    if (bh > LTHR || bw > LTHR) {
      int pos = atomicAdd(&cellCnt[b * 65 + 64], 1);
      if (pos < LARGECAP) largeList[b * LARGECAP + pos] = (u16)r;
    } else {
      int gy = min(7, max(0, (int)((o.x + o.z) * 4.0f)));
      int gx = min(7, max(0, (int)((o.y + o.w) * 4.0f)));
      int cell = gy * 8 + gx;
      int pos = atomicAdd(&cellCnt[b * 65 + cell], 1);
      if (pos < CELLCAP) cellList[((size_t)b * 64 + cell) * CELLCAP + pos] = (u16)r;
    }
  }
}

// K4: blocks 0..63 = per-cell {self + boundary-band-filtered cross};
// blocks 64..127 = large-box window tests + large-large pairs.
__global__ __launch_bounds__(256) void pairs_kernel(const float4* __restrict__ boxes,
                                                    const u16* __restrict__ cellList,
                                                    const u16* __restrict__ largeList,
                                                    const int* __restrict__ cellCnt,
                                                    u64* __restrict__ tileT,
                                                    u32* __restrict__ sent,
                                                    int* __restrict__ scnt) {
  int b = blockIdx.y;
  int tid = threadIdx.x;
  if (blockIdx.x >= 64) {
    // ---- large path ----
    int lb = blockIdx.x - 64;  // 0..63
    int nL = min(cellCnt[b * 65 + 64], LARGECAP);
    if (nL == 0) return;
    for (int li = lb; li < nL; li += 64) {
      int L = largeList[b * LARGECAP + li];
      float4 Lb = boxes[(size_t)b * NPAD + L];
      float hL = Lb.z - Lb.x, wL = Lb.w - Lb.y;
      if (0.7f * hL >= 0.126f || 0.7f * wL >= 0.126f) continue;  // no small can match
      float La = hL * wL;
      float sLy = Lb.x + Lb.z, sLx = Lb.y + Lb.w;
      int gy0 = max(0, (int)((sLy - 0.08f) * 4.0f));
      int gy1 = min(7, (int)((sLy + 0.08f) * 4.0f));
      int gx0 = max(0, (int)((sLx - 0.08f) * 4.0f));
      int gx1 = min(7, (int)((sLx + 0.08f) * 4.0f));
      for (int gy = gy0; gy <= gy1; ++gy)
        for (int gx = gx0; gx <= gx1; ++gx) {
          int cc = gy * 8 + gx;
          int cnt = min(cellCnt[b * 65 + cc], CELLCAP);
          for (int i = tid; i < cnt; i += 256) {
            int r = cellList[((size_t)b * 64 + cc) * CELLCAP + i];
            float4 jb = boxes[(size_t)b * NPAD + r];
            float ja = (jb.z - jb.x) * (jb.w - jb.y);
            if (iou_gt(Lb, jb, La, ja)) emit_pair(b, L, r, tileT, sent, scnt);
          }
        }
    }
    // large-large, list-index i<j
    int s = 1;
    while ((1 << s) < nL) ++s;
    int tot = nL << s, m = (1 << s) - 1;
    int stride = 64 * 256;
    for (int t = lb * 256 + tid; t < tot; t += stride) {
      int i = t >> s, j = t & m;
      if (j >= nL || i >= j) continue;
      int Li = largeList[b * LARGECAP + i];
      int Lj = largeList[b * LARGECAP + j];
      float4 A = boxes[(size_t)b * NPAD + Li];
      float4 B = boxes[(size_t)b * NPAD + Lj];
      float aA = (A.z - A.x) * (A.w - A.y);
      float aB = (B.z - B.x) * (B.w - B.y);
      if (iou_gt(A, B, aA, aB)) emit_pair(b, Li, Lj, tileT, sent, scnt);
    }
    return;
  }
  // ---- cell path ----
  int c = blockIdx.x;
  int cy = c >> 3, cx = c & 7;
  int nA = min(cellCnt[b * 65 + c], CELLCAP);
  if (nA == 0) return;
  __shared__ float4 Ab[CELLCAP];
  __shared__ float Aa[CELLCAP];
  __shared__ float Asx[CELLCAP];  // x1+x2 = 2*center_x
  __shared__ float Asy[CELLCAP];  // y1+y2 = 2*center_y
  __shared__ u16 Ai[CELLCAP];
  __shared__ u16 fAi[CELLCAP];
  __shared__ float4 Bb[3 * CELLCAP];
  __shared__ float Ba[3 * CELLCAP];
  __shared__ u16 Bi[3 * CELLCAP];
  __shared__ int nfA_s, nfB_s;
  for (int i = tid; i < nA; i += 256) {
    int r = cellList[((size_t)b * 64 + c) * CELLCAP + i];
    float4 bx = boxes[(size_t)b * NPAD + r];
    Ab[i] = bx;
    Aa[i] = (bx.z - bx.x) * (bx.w - bx.y);
    Asy[i] = bx.x + bx.z;
    Asx[i] = bx.y + bx.w;
    Ai[i] = (u16)r;
  }
  __syncthreads();
  // self pairs: exact triangular enumeration
  {
    int totS = (nA * (nA - 1)) >> 1;
    for (int t = tid; t < totS; t += 256) {
      int i = (int)((1.0f + sqrtf(8.0f * (float)t + 1.0f)) * 0.5f);
      int tri = (i * (i - 1)) >> 1;
      if (t < tri) {
        --i;
        tri = (i * (i - 1)) >> 1;
      } else if (t >= tri + i) {
        tri += i;
        ++i;
      }
      int j = t - tri;
      if (iou_gt(Ab[i], Ab[j], Aa[i], Aa[j]))
        emit_pair(b, Ai[i], Ai[j], tileT, sent, scnt);
    }
  }
  // phase R: right neighbor, x boundary band
  if (cx < 7) {
    __syncthreads();
    if (tid == 0) { nfA_s = 0; nfB_s = 0; }
    __syncthreads();
    float XR2 = (float)(cx + 1) * 0.25f;
    for (int i = tid; i < nA; i += 256)
      if (Asx[i] > XR2 - 0.078f) fAi[atomicAdd(&nfA_s, 1)] = (u16)i;
    int nc = c + 1;
    int nN = min(cellCnt[b * 65 + nc], CELLCAP);
    for (int i = tid; i < nN; i += 256) {
      int r = cellList[((size_t)b * 64 + nc) * CELLCAP + i];
      float4 bx = boxes[(size_t)b * NPAD + r];
      if (bx.y + bx.w < XR2 + 0.078f) {
        int p = atomicAdd(&nfB_s, 1);
        Bb[p] = bx;
        Ba[p] = (bx.z - bx.x) * (bx.w - bx.y);
        Bi[p] = (u16)r;
      }
    }
    __syncthreads();
    int nfA = nfA_s, nfB = nfB_s;
    if (nfA && nfB) {
      int s = 1;
      while ((1 << s) < nfB) ++s;
      int tot = nfA << s, m = (1 << s) - 1;
      for (int t = tid; t < tot; t += 256) {
        int ii = fAi[t >> s], j = t & m;
        if (j < nfB && iou_gt(Ab[ii], Bb[j], Aa[ii], Ba[j]))
          emit_pair(b, Ai[ii], Bi[j], tileT, sent, scnt);
      }
    }
  }
  // phase D: three lower neighbors, y band (+x band for diagonals at staging)
  if (cy < 7) {
    __syncthreads();
    if (tid == 0) { nfA_s = 0; nfB_s = 0; }
    __syncthreads();
    float YB2 = (float)(cy + 1) * 0.25f;
    float XL2 = (float)cx * 0.25f;
    float XR2 = (float)(cx + 1) * 0.25f;
    for (int i = tid; i < nA; i += 256)
      if (Asy[i] > YB2 - 0.078f) fAi[atomicAdd(&nfA_s, 1)] = (u16)i;
    for (int k = 0; k < 3; ++k) {
      int nx = cx + k - 1;
      if (nx < 0 || nx > 7) continue;
      int nc = (cy + 1) * 8 + nx;
      int nN = min(cellCnt[b * 65 + nc], CELLCAP);
      for (int i = tid; i < nN; i += 256) {
        int r = cellList[((size_t)b * 64 + nc) * CELLCAP + i];
        float4 bx = boxes[(size_t)b * NPAD + r];
        float bsy = bx.x + bx.z, bsx = bx.y + bx.w;
        bool ok = bsy < YB2 + 0.078f;
        if (k == 0) ok = ok && (bsx > XL2 - 0.078f);
        if (k == 2) ok = ok && (bsx < XR2 + 0.078f);
        if (ok) {
          int p = atomicAdd(&nfB_s, 1);
          Bb[p] = bx;
          Ba[p] = (bx.z - bx.x) * (bx.w - bx.y);
          Bi[p] = (u16)r;
        }
      }
    }
    __syncthreads();
    int nfA = nfA_s, nfB = nfB_s;
    if (nfA && nfB) {
      int s = 1;
      while ((1 << s) < nfB) ++s;
      int tot = nfA << s, m = (1 << s) - 1;
      for (int t = tid; t < tot; t += 256) {
        int ii = fAi[t >> s], j = t & m;
        if (j < nfB && iou_gt(Ab[ii], Bb[j], Aa[ii], Ba[j]))
          emit_pair(b, Ai[ii], Bi[j], tileT, sent, scnt);
      }
    }
  }
}

// K5: greedy NMS, 256-box TILE scan (round-4 verified version).
__global__ __launch_bounds__(512) void nms_kernel(const u32* __restrict__ sent,
                                                  const int* __restrict__ scnt,
                                                  const u64* __restrict__ tileT,
                                                  const float4* __restrict__ boxes,
                                                  float4* __restrict__ out) {
  int b = blockIdx.x;
  int tid = threadIdx.x;
  int lane = tid & 63;
  int wv = tid >> 6;
  __shared__ u32 entS[LDSE];        // 49152 B
  __shared__ u32 rmb[TILE];         // 1024 B
  __shared__ u64 Kall[NWORD];       // 768 B
  __shared__ int cw[NT];
  __shared__ int prefix[NT + 1];
  __shared__ int baseT[NT];
  if (tid < NT) cw[tid] = min(scnt[b * NT + tid], SCAP);
  if (tid < TILE) rmb[tid] = 0u;
  if (tid < NWORD) Kall[tid] = 0ULL;
  {
    float4 z = {0.f, 0.f, 0.f, 0.f};
    for (int i = tid; i < PROP; i += 512) out[(size_t)b * PROP + i] = z;
  }
  __syncthreads();
  if (tid == 0) {
    int run = 0;
    for (int t = 0; t < NT; ++t) { prefix[t] = run; run += cw[t]; }
    prefix[NT] = run;
  }
  __syncthreads();
  for (int t = wv; t < NT; t += 8) {
    const u32* gb = sent + (size_t)(b * NT + t) * SCAP;
    int base = prefix[t], n = cw[t];
    for (int e = lane; e < n; e += 64) {
      int slot = base + e;
      if (slot < LDSE) entS[slot] = gb[e];
    }
  }
  __syncthreads();
  if (wv == 0) {
    const u64* tb0 = tileT + (size_t)b * (NT * TILE * 4);
    u64 mc[4][4], mn[4][4];
#pragma unroll
    for (int q = 0; q < 4; ++q)
#pragma unroll
      for (int j = 0; j < 4; ++j)
        mc[q][j] = tb0[(size_t)(q * 64 + lane) * 4 + j];
    int total = 0;
    for (int t = 0; t < NT; ++t) {
      if (t + 1 < NT) {
        const u64* nb = tb0 + (size_t)(t + 1) * (TILE * 4);
#pragma unroll
        for (int q = 0; q < 4; ++q)
#pragma unroll
          for (int j = 0; j < 4; ++j)
            mn[q][j] = nb[(size_t)(q * 64 + lane) * 4 + j];
      }
      {
        int n = cw[t], base = prefix[t];
        for (int e = lane; e < n; e += 64) {
          int slot = base + e;
          u32 ent = (slot < LDSE) ? entS[slot] : sent[(size_t)(b * NT + t) * SCAP + e];
          int srcr = (int)(ent >> 8);
          if ((Kall[srcr >> 6] >> (srcr & 63)) & 1ULL) rmb[ent & 255] = 1u;
        }
      }
      u32 f0 = rmb[lane], f1 = rmb[64 + lane], f2 = rmb[128 + lane], f3 = rmb[192 + lane];
      rmb[lane] = 0u;
      rmb[64 + lane] = 0u;
      rmb[128 + lane] = 0u;
      rmb[192 + lane] = 0u;
      int gw = t * 4;
      u64 K0, K1, K2, K3;
      {
        bool alive0 = (f0 == 0u) && ((valid_mask(gw) >> lane) & 1ULL);
        u64 cm = mc[0][0];
        u64 K = __ballot(alive0);
        for (int it = 0; it < 70; ++it) {
          bool alive = alive0 && ((K & cm) == 0ULL);
          u64 Kn = __ballot(alive);
          if (Kn == K) break;
          K = Kn;
        }
        K0 = K;
      }
      {
        u64 pre = K0 & mc[1][0];
        bool alive0 = (f1 == 0u) && ((valid_mask(gw + 1) >> lane) & 1ULL) && (pre == 0ULL);
        u64 cm = mc[1][1];
        u64 K = __ballot(alive0);
        for (int it = 0; it < 70; ++it) {
          bool alive = alive0 && ((K & cm) == 0ULL);
          u64 Kn = __ballot(alive);
          if (Kn == K) break;
          K = Kn;
        }
        K1 = K;
      }
      {
        u64 pre = (K0 & mc[2][0]) | (K1 & mc[2][1]);
        bool alive0 = (f2 == 0u) && ((valid_mask(gw + 2) >> lane) & 1ULL) && (pre == 0ULL);
        u64 cm = mc[2][2];
        u64 K = __ballot(alive0);
        for (int it = 0; it < 70; ++it) {
          bool alive = alive0 && ((K & cm) == 0ULL);
          u64 Kn = __ballot(alive);
          if (Kn == K) break;
          K = Kn;
        }
        K2 = K;
      }
      {
        u64 pre = (K0 & mc[3][0]) | (K1 & mc[3][1]) | (K2 & mc[3][2]);
        bool alive0 = (f3 == 0u) && ((valid_mask(gw + 3) >> lane) & 1ULL) && (pre == 0ULL);
        u64 cm = mc[3][3];
        u64 K = __ballot(alive0);
        for (int it = 0; it < 70; ++it) {
          bool alive = alive0 && ((K & cm) == 0ULL);
          u64 Kn = __ballot(alive);
          if (Kn == K) break;
          K = Kn;
        }
        K3 = K;
      }
      if (lane == 0) {
        Kall[gw] = K0;
        Kall[gw + 1] = K1;
        Kall[gw + 2] = K2;
        Kall[gw + 3] = K3;
        baseT[t] = total;
      }
      total += __popcll(K0) + __popcll(K1) + __popcll(K2) + __popcll(K3);
#pragma unroll
      for (int q = 0; q < 4; ++q)
#pragma unroll
        for (int j = 0; j < 4; ++j)
          mc[q][j] = mn[q][j];
    }
  }
  __syncthreads();
  for (int i = tid; i < NSEL; i += 512) {
    int g = i >> 6, bb = i & 63;
    u64 K = Kall[g];
    if ((K >> bb) & 1ULL) {
      int t = i >> 8;
      int rank = baseT[t];
      for (int q = t * 4; q < g; ++q) rank += __popcll(Kall[q]);
      rank += __popcll(K & ((1ULL << bb) - 1ULL));
      if (rank < PROP) out[(size_t)b * PROP + rank] = boxes[(size_t)b * NPAD + i];
    }
  }
}

extern "C" void kernel_launch(void* const* d_in, const int* in_sizes, int n_in,
                              void* d_out, int out_size, void* d_ws, size_t ws_size,
                              hipStream_t stream) {
  const float* probs = (const float*)d_in[0];    // (8,131072,2)
  const float* deltas = (const float*)d_in[1];   // (8,131072,4)
  const float* anchors = (const float*)d_in[2];  // (8,131072,4)
  char* ws = (char*)d_ws;
  int* histPB = (int*)(ws + OFF_HISTPB);
  int* bfill = (int*)(ws + OFF_BFILL);
  int* scnt = (int*)(ws + OFF_SCNT);
  int* cellCnt = (int*)(ws + OFF_CELLCNT);
  u64* tileT = (u64*)(ws + OFF_TILET);
  u64* cand = (u64*)(ws + OFF_CAND);
  float4* boxes = (float4*)(ws + OFF_BOXES);
  u16* cellList = (u16*)(ws + OFF_CELLLIST);
  u16* largeList = (u16*)(ws + OFF_LARGE);
  u32* sent = (u32*)(ws + OFF_SENT);

  hist_kernel<<<dim3(HB, BATCH), 256, 0, stream>>>(probs, histPB, bfill, scnt, cellCnt);
  gather_kernel<<<dim3(64, BATCH), 256, 0, stream>>>(probs, histPB, bfill, cand);
  sortdecode_kernel<<<dim3(64, BATCH), 256, 0, stream>>>(histPB, bfill, cand, anchors,
                                                         deltas, boxes, cellCnt,
                                                         cellList, largeList, tileT);
  pairs_kernel<<<dim3(128, BATCH), 256, 0, stream>>>(boxes, cellList, largeList,
                                                     cellCnt, tileT, sent, scnt);
  nms_kernel<<<BATCH, 512, 0, stream>>>(sent, scnt, tileT, boxes, (float4*)d_out);
}